// Round 14
// baseline (247.800 us; speedup 1.0000x reference)
//
#include <hip/hip_runtime.h>
#include <math.h>

#define HEADS 4
#define HID 64
#define BSHIFT 7          // 128 nodes per bucket
#define BWIDTH 128
#define CCAP 4096         // LDS csr-staging capacity (edges/bucket mean ~2047)
#define DCHUNK 8192       // edges per k_bdist block (8 per thread, 1024 threads)

typedef __attribute__((ext_vector_type(8))) short short8;
typedef __attribute__((ext_vector_type(4))) float f32x4;
typedef __attribute__((ext_vector_type(2))) float f32x2;

__device__ __forceinline__ float lrelu(float x) { return x > 0.f ? x : 0.2f * x; }

__device__ __forceinline__ unsigned short bf16r(float f) {
    unsigned u = __float_as_uint(f);
    unsigned r = (u + 0x7FFFu + ((u >> 16) & 1u)) >> 16;
    return (unsigned short)r;
}
__device__ __forceinline__ f32x2 unpk(unsigned u) {
    f32x2 r;
    r.x = __uint_as_float(u << 16);
    r.y = __uint_as_float(u & 0xffff0000u);
    return r;
}

__device__ __forceinline__ float wred_sum(float v) {
#pragma unroll
    for (int o = 32; o > 0; o >>= 1) v += __shfl_xor(v, o);
    return v;
}
__device__ __forceinline__ float red16_sum(float v) {
#pragma unroll
    for (int o = 8; o > 0; o >>= 1) v += __shfl_xor(v, o);
    return v;
}

// ======================= CSR build: two-level LDS counting sort =======================
__global__ void k_bhist(const int* __restrict__ dstI, int* __restrict__ bcnt,
                        int E, int NBUCK) {
    __shared__ int h[1024];
    for (int i = threadIdx.x; i < NBUCK; i += 256) h[i] = 0;
    __syncthreads();
    int stride = gridDim.x * 256;
    for (int e = blockIdx.x * 256 + threadIdx.x; e < E; e += stride)
        atomicAdd(&h[dstI[e] >> BSHIFT], 1);
    __syncthreads();
    for (int i = threadIdx.x; i < NBUCK; i += 256)
        if (h[i]) atomicAdd(&bcnt[i], h[i]);
}

__global__ void k_bscan(const int* __restrict__ bcnt, int* __restrict__ bbase,
                        int* __restrict__ gcur, int* __restrict__ off,
                        int NBUCK, int N, int E) {
    __shared__ int lds[1024];
    int t = threadIdx.x;
    int v = (t < NBUCK) ? bcnt[t] : 0;
    lds[t] = v;
    __syncthreads();
    for (int s = 1; s < 1024; s <<= 1) {
        int u = (t >= s) ? lds[t - s] : 0;
        __syncthreads();
        lds[t] += u;
        __syncthreads();
    }
    if (t < NBUCK) {
        int b = lds[t] - v;
        bbase[t] = b;
        gcur[t] = b;
    }
    if (t == 0) { bbase[NBUCK] = E; off[N] = E; }
}

__global__ void k_bdist(const int* __restrict__ srcI, const int* __restrict__ dstI,
                        int* __restrict__ gcur, unsigned* __restrict__ pairs,
                        int E, int NBUCK) {
    __shared__ int h[1024];
    __shared__ int cur[1024];
    for (int i = threadIdx.x; i < NBUCK; i += 1024) h[i] = 0;
    __syncthreads();
    int base = blockIdx.x * DCHUNK;
    int sr[8], dr[8];
#pragma unroll
    for (int k = 0; k < 8; k++) {
        int e = base + threadIdx.x + k * 1024;
        if (e < E) {
            sr[k] = srcI[e];
            dr[k] = dstI[e];
            atomicAdd(&h[dr[k] >> BSHIFT], 1);
        } else dr[k] = -1;
    }
    __syncthreads();
    for (int i = threadIdx.x; i < NBUCK; i += 1024)
        cur[i] = h[i] ? atomicAdd(&gcur[i], h[i]) : 0;
    __syncthreads();
#pragma unroll
    for (int k = 0; k < 8; k++) {
        if (dr[k] >= 0) {
            int b = dr[k] >> BSHIFT;
            int p = atomicAdd(&cur[b], 1);
            pairs[p] = ((unsigned)sr[k] << BSHIFT) | ((unsigned)dr[k] & (BWIDTH - 1));
        }
    }
}

__global__ void k_bcsr(const unsigned* __restrict__ pairs, const int* __restrict__ bbase,
                       int* __restrict__ off, int* __restrict__ csr, int N) {
    __shared__ int cnt[BWIDTH];
    __shared__ int scan[BWIDTH];
    __shared__ int cur[BWIDTH];
    __shared__ int stage[CCAP];
    int b = blockIdx.x;
    int nodeBase = b << BSHIFT;
    int nNodes = N - nodeBase;
    if (nNodes > BWIDTH) nNodes = BWIDTH;
    int e0 = bbase[b], e1 = bbase[b + 1];
    int ecnt = e1 - e0;
    if (threadIdx.x < BWIDTH) cnt[threadIdx.x] = 0;
    __syncthreads();
    for (int i = threadIdx.x; i < ecnt; i += 256)
        atomicAdd(&cnt[pairs[e0 + i] & (BWIDTH - 1)], 1);
    __syncthreads();
    if (threadIdx.x < BWIDTH)
        scan[threadIdx.x] = (threadIdx.x < nNodes) ? cnt[threadIdx.x] : 0;
    __syncthreads();
    for (int s = 1; s < BWIDTH; s <<= 1) {
        int u = 0;
        if (threadIdx.x < BWIDTH && threadIdx.x >= s) u = scan[threadIdx.x - s];
        __syncthreads();
        if (threadIdx.x < BWIDTH) scan[threadIdx.x] += u;
        __syncthreads();
    }
    if (threadIdx.x < nNodes) {
        int ex = scan[threadIdx.x] - cnt[threadIdx.x];
        off[nodeBase + threadIdx.x] = e0 + ex;
        cur[threadIdx.x] = ex;
    }
    __syncthreads();
    for (int i = threadIdx.x; i < ecnt; i += 256) {
        unsigned pr = pairs[e0 + i];
        int l = atomicAdd(&cur[pr & (BWIDTH - 1)], 1);
        int src = (int)(pr >> BSHIFT);
        if (l < CCAP) stage[l] = src;
        else csr[e0 + l] = src;
    }
    __syncthreads();
    int lim = ecnt < CCAP ? ecnt : CCAP;
    for (int i = threadIdx.x; i < lim; i += 256) csr[e0 + i] = stage[i];
}

// ======================= fused prep: W1-proj, W2-proj, W2->bf16, out-zero =======================
__device__ __forceinline__ void prep_body(const float* __restrict__ W,
                                          const float* __restrict__ asrc,
                                          const float* __restrict__ adst,
                                          float* __restrict__ p_src,
                                          float* __restrict__ p_dst, int K, int blk) {
    int wid = blk * 4 + (threadIdx.x >> 6);
    int lane = threadIdx.x & 63;
    int total = K * 4 * 2;
    if (wid >= total) return;
    int which = wid / (K * 4);
    int hk = wid % (K * 4);
    int h = hk / K, k = hk % K;
    const float* a = which ? adst : asrc;
    float v = W[(size_t)k * 256 + h * 64 + lane] * a[h * 64 + lane];
    v = wred_sum(v);
    if (lane == 0) (which ? p_dst : p_src)[h * K + k] = v;
}

// blocks [0,6): W1 proj; [6,134): W2 proj; [134,198): W2->bf16 transpose + out zero
__global__ void k_prep_all(const float* __restrict__ W1, const float* __restrict__ as1,
                           const float* __restrict__ ad1, const float* __restrict__ W2,
                           const float* __restrict__ as2, const float* __restrict__ ad2,
                           float* __restrict__ p1s, float* __restrict__ p1d,
                           float* __restrict__ qs, float* __restrict__ qd,
                           unsigned short* __restrict__ W2bt, float* __restrict__ out,
                           int outTotal) {
    int b = blockIdx.x;
    if (b < 6) {
        prep_body(W1, as1, ad1, p1s, p1d, 3, b);
    } else if (b < 134) {
        prep_body(W2, as2, ad2, qs, qd, 64, b - 6);
    } else {
        int i = (b - 134) * 256 + threadIdx.x;
        int c = i >> 8, kh = i & 255;
        int h = kh >> 6, kf = kh & 63;
        W2bt[i] = bf16r(W2[kf * 256 + h * 64 + c]);
        if (i < outTotal) out[i] = 0.f;
    }
}

// ======================= layer 1: 16-lane group per node, single pass =======================
// es computed inline from gathered x[s] (ps is 12 floats, L1-resident); ed from x[wid].
__global__ void k_agg1(const int* __restrict__ off, const int* __restrict__ csr,
                       const float* __restrict__ x, const float* __restrict__ ps,
                       const float* __restrict__ pd, const float* __restrict__ W1,
                       const float* __restrict__ b1, const float* __restrict__ qs,
                       const float* __restrict__ qd, unsigned short* __restrict__ houtb,
                       float* __restrict__ es2, float* __restrict__ ed2, int N) {
    int grp = (blockIdx.x * blockDim.x + threadIdx.x) >> 4;
    int l = threadIdx.x & 15;
    int wid = grp;
    bool active = wid < N;
    int o0 = 0, deg = 0;
    float ed0 = 0.f, ed1 = 0.f, ed2v = 0.f, ed3 = 0.f;
    if (active) {
        o0 = off[wid];
        deg = off[wid + 1] - o0;
        float y0 = x[wid * 3], y1 = x[wid * 3 + 1], y2 = x[wid * 3 + 2];
        ed0 = y0 * pd[0] + y1 * pd[1] + y2 * pd[2];
        ed1 = y0 * pd[3] + y1 * pd[4] + y2 * pd[5];
        ed2v = y0 * pd[6] + y1 * pd[7] + y2 * pd[8];
        ed3 = y0 * pd[9] + y1 * pd[10] + y2 * pd[11];
    }

    float t0 = 0.f, t1 = 0.f, t2 = 0.f, t3 = 0.f;
    float a00 = 0, a01 = 0, a02 = 0, a10 = 0, a11 = 0, a12 = 0;
    float a20 = 0, a21 = 0, a22 = 0, a30 = 0, a31 = 0, a32 = 0;
    for (int j = l; j < deg; j += 16) {
        int s = csr[o0 + j];
        float xv0 = x[s * 3], xv1 = x[s * 3 + 1], xv2 = x[s * 3 + 2];
        float e0 = __expf(lrelu(xv0 * ps[0] + xv1 * ps[1] + xv2 * ps[2] + ed0));
        float e1 = __expf(lrelu(xv0 * ps[3] + xv1 * ps[4] + xv2 * ps[5] + ed1));
        float e2 = __expf(lrelu(xv0 * ps[6] + xv1 * ps[7] + xv2 * ps[8] + ed2v));
        float e3 = __expf(lrelu(xv0 * ps[9] + xv1 * ps[10] + xv2 * ps[11] + ed3));
        t0 += e0; t1 += e1; t2 += e2; t3 += e3;
        a00 += e0 * xv0; a01 += e0 * xv1; a02 += e0 * xv2;
        a10 += e1 * xv0; a11 += e1 * xv1; a12 += e1 * xv2;
        a20 += e2 * xv0; a21 += e2 * xv1; a22 += e2 * xv2;
        a30 += e3 * xv0; a31 += e3 * xv1; a32 += e3 * xv2;
    }
    t0 = red16_sum(t0); t1 = red16_sum(t1); t2 = red16_sum(t2); t3 = red16_sum(t3);
    float i0 = t0 > 0.f ? 1.f / t0 : 0.f;
    float i1 = t1 > 0.f ? 1.f / t1 : 0.f;
    float i2 = t2 > 0.f ? 1.f / t2 : 0.f;
    float i3 = t3 > 0.f ? 1.f / t3 : 0.f;
    a00 = red16_sum(a00) * i0; a01 = red16_sum(a01) * i0; a02 = red16_sum(a02) * i0;
    a10 = red16_sum(a10) * i1; a11 = red16_sum(a11) * i1; a12 = red16_sum(a12) * i1;
    a20 = red16_sum(a20) * i2; a21 = red16_sum(a21) * i2; a22 = red16_sum(a22) * i2;
    a30 = red16_sum(a30) * i3; a31 = red16_sum(a31) * i3; a32 = red16_sum(a32) * i3;

    if (!active) return;

    const float4* W1f = (const float4*)W1;
    float4 r = make_float4(0.f, 0.f, 0.f, 0.f);
    float ah[4][3] = {{a00, a01, a02}, {a10, a11, a12}, {a20, a21, a22}, {a30, a31, a32}};
#pragma unroll
    for (int k = 0; k < 3; k++) {
#pragma unroll
        for (int h = 0; h < 4; h++) {
            float4 wv = W1f[k * 64 + h * 16 + l];
            float a = ah[h][k];
            r.x += a * wv.x; r.y += a * wv.y; r.z += a * wv.z; r.w += a * wv.w;
        }
    }
    float4 bv = ((const float4*)b1)[l];
    float4 hv;
    hv.x = fmaxf(0.25f * r.x + bv.x, 0.f);
    hv.y = fmaxf(0.25f * r.y + bv.y, 0.f);
    hv.z = fmaxf(0.25f * r.z + bv.z, 0.f);
    hv.w = fmaxf(0.25f * r.w + bv.w, 0.f);
    ((ushort4*)houtb)[(size_t)wid * 16 + l] =
        make_ushort4(bf16r(hv.x), bf16r(hv.y), bf16r(hv.z), bf16r(hv.w));

    const float4* qsf = (const float4*)qs;
    const float4* qdf = (const float4*)qd;
    float psv[4], pdv[4];
#pragma unroll
    for (int h = 0; h < 4; h++) {
        float4 q = qsf[h * 16 + l];
        psv[h] = red16_sum(hv.x * q.x + hv.y * q.y + hv.z * q.z + hv.w * q.w);
        float4 p = qdf[h * 16 + l];
        pdv[h] = red16_sum(hv.x * p.x + hv.y * p.y + hv.z * p.z + hv.w * p.w);
    }
    if (l == 0) {
        ((float4*)es2)[wid] = make_float4(psv[0], psv[1], psv[2], psv[3]);
        ((float4*)ed2)[wid] = make_float4(pdv[0], pdv[1], pdv[2], pdv[3]);
    }
}

// ======================= layer 2: softmax -> LDS; phase-B packed f32x2 gather =======================
#define NS 16
__global__ void k_agg2(const int* __restrict__ off, const int* __restrict__ csr,
                       const float* __restrict__ es, const float* __restrict__ ed,
                       const unsigned short* __restrict__ houtb,
                       unsigned short* __restrict__ aggb, int N) {
    __shared__ float exl[NS * 64 * 4];
    __shared__ int   sl[NS * 64];
    __shared__ float minv[NS * 4];
    __shared__ int   meta[NS * 2];

    int l = threadIdx.x & 15;
    int slot = threadIdx.x >> 4;
    int wid = blockIdx.x * NS + slot;
    bool active = wid < N;
    int o0 = 0, deg = 0;
    float4 edv = make_float4(0.f, 0.f, 0.f, 0.f);
    if (active) {
        o0 = off[wid];
        deg = off[wid + 1] - o0;
        edv = ((const float4*)ed)[wid];
    }

    // phase A: exp (no max) -> LDS (first 64 edges) + sum
    float t0 = 0.f, t1 = 0.f, t2 = 0.f, t3 = 0.f;
    for (int j = l; j < deg; j += 16) {
        int s = csr[o0 + j];
        float4 ev = ((const float4*)es)[s];
        float e0 = __expf(lrelu(ev.x + edv.x));
        float e1 = __expf(lrelu(ev.y + edv.y));
        float e2 = __expf(lrelu(ev.z + edv.z));
        float e3 = __expf(lrelu(ev.w + edv.w));
        if (j < 64) {
            ((float4*)exl)[slot * 64 + j] = make_float4(e0, e1, e2, e3);
            sl[slot * 64 + j] = s;
        }
        t0 += e0; t1 += e1; t2 += e2; t3 += e3;
    }
    {
        int dmain = deg < 64 ? deg : 64;
        int d8 = (dmain + 7) & ~7;
        if (dmain + l < d8) {
            ((float4*)exl)[slot * 64 + dmain + l] = make_float4(0.f, 0.f, 0.f, 0.f);
            sl[slot * 64 + dmain + l] = 0;
        }
    }
    t0 = red16_sum(t0); t1 = red16_sum(t1); t2 = red16_sum(t2); t3 = red16_sum(t3);
    if (l == 0) {
        minv[slot * 4 + 0] = t0 > 0.f ? 1.f / t0 : 0.f;
        minv[slot * 4 + 1] = t1 > 0.f ? 1.f / t1 : 0.f;
        minv[slot * 4 + 2] = t2 > 0.f ? 1.f / t2 : 0.f;
        minv[slot * 4 + 3] = t3 > 0.f ? 1.f / t3 : 0.f;
        meta[slot * 2 + 0] = o0;
        meta[slot * 2 + 1] = deg;
    }
    __syncthreads();

    int lane = threadIdx.x & 63;
    int w = threadIdx.x >> 6;
    int half = lane >> 5;
    int c2 = lane & 31;
    for (int sidx = 0; sidx < 4; sidx++) {
        int slot2 = w * 4 + sidx;
        int nd = blockIdx.x * NS + slot2;
        if (nd >= N) continue;
        int o0b = meta[slot2 * 2 + 0], degb = meta[slot2 * 2 + 1];
        float iv0 = minv[slot2 * 4 + 0], iv1 = minv[slot2 * 4 + 1];
        float iv2 = minv[slot2 * 4 + 2], iv3 = minv[slot2 * 4 + 3];

        f32x2 q0 = {0.f, 0.f}, q1 = {0.f, 0.f}, q2 = {0.f, 0.f}, q3 = {0.f, 0.f};
        const float4* EX = ((const float4*)exl) + slot2 * 64;
        const int* S = sl + slot2 * 64;
        int dmain = degb < 64 ? degb : 64;
        int d8 = (dmain + 7) & ~7;
        for (int j = 0; j < d8; j += 8) {
            float4 a0 = EX[j + half];
            float4 a1 = EX[j + 2 + half];
            float4 a2 = EX[j + 4 + half];
            float4 a3 = EX[j + 6 + half];
            int s0 = S[j + half], s1 = S[j + 2 + half];
            int s2 = S[j + 4 + half], s3 = S[j + 6 + half];
            unsigned u0 = *(const unsigned*)(houtb + (size_t)s0 * 64 + 2 * c2);
            unsigned u1 = *(const unsigned*)(houtb + (size_t)s1 * 64 + 2 * c2);
            unsigned u2 = *(const unsigned*)(houtb + (size_t)s2 * 64 + 2 * c2);
            unsigned u3 = *(const unsigned*)(houtb + (size_t)s3 * 64 + 2 * c2);
            f32x2 v0 = unpk(u0), v1 = unpk(u1), v2 = unpk(u2), v3 = unpk(u3);
            q0 += a0.x * v0; q0 += a1.x * v1; q0 += a2.x * v2; q0 += a3.x * v3;
            q1 += a0.y * v0; q1 += a1.y * v1; q1 += a2.y * v2; q1 += a3.y * v3;
            q2 += a0.z * v0; q2 += a1.z * v1; q2 += a2.z * v2; q2 += a3.z * v3;
            q3 += a0.w * v0; q3 += a1.w * v1; q3 += a2.w * v2; q3 += a3.w * v3;
        }
        if (degb > 64) {
            float4 edv2 = ((const float4*)ed)[nd];
            for (int j = 64 + half; j < degb; j += 2) {
                int s = csr[o0b + j];
                float4 ev = ((const float4*)es)[s];
                float e0 = __expf(lrelu(ev.x + edv2.x));
                float e1 = __expf(lrelu(ev.y + edv2.y));
                float e2 = __expf(lrelu(ev.z + edv2.z));
                float e3 = __expf(lrelu(ev.w + edv2.w));
                unsigned u = *(const unsigned*)(houtb + (size_t)s * 64 + 2 * c2);
                f32x2 v = unpk(u);
                q0 += e0 * v; q1 += e1 * v; q2 += e2 * v; q3 += e3 * v;
            }
        }
        q0.x += __shfl_xor(q0.x, 32); q0.y += __shfl_xor(q0.y, 32);
        q1.x += __shfl_xor(q1.x, 32); q1.y += __shfl_xor(q1.y, 32);
        q2.x += __shfl_xor(q2.x, 32); q2.y += __shfl_xor(q2.y, 32);
        q3.x += __shfl_xor(q3.x, 32); q3.y += __shfl_xor(q3.y, 32);

        if (half == 0) {
            size_t b = (size_t)nd * 256;
            unsigned w0 = (unsigned)bf16r(q0.x * iv0) | ((unsigned)bf16r(q0.y * iv0) << 16);
            unsigned w1 = (unsigned)bf16r(q1.x * iv1) | ((unsigned)bf16r(q1.y * iv1) << 16);
            unsigned w2 = (unsigned)bf16r(q2.x * iv2) | ((unsigned)bf16r(q2.y * iv2) << 16);
            unsigned w3 = (unsigned)bf16r(q3.x * iv3) | ((unsigned)bf16r(q3.y * iv3) << 16);
            *(unsigned*)(aggb + b + 2 * c2)        = w0;
            *(unsigned*)(aggb + b + 64 + 2 * c2)   = w1;
            *(unsigned*)(aggb + b + 128 + 2 * c2)  = w2;
            *(unsigned*)(aggb + b + 192 + 2 * c2)  = w3;
        }
    }
}

// ======================= layer 2 output transform (MFMA) + fused global-add-pool =======================
__global__ void k_out2(const unsigned short* __restrict__ aggb,
                       const unsigned short* __restrict__ W2bt,
                       const float* __restrict__ b2, const int* __restrict__ batch,
                       float* __restrict__ out, int N) {
    int w = threadIdx.x >> 6, lane = threadIdx.x & 63;
    int nodeBase = blockIdx.x * 64 + w * 16;
    int m = lane & 15;
    int quad = lane >> 4;
    const short* A = (const short*)aggb + (size_t)(nodeBase + m) * 256 + quad * 8;
    const short* B = (const short*)W2bt;

    f32x4 acc0 = {0.f, 0.f, 0.f, 0.f}, acc1 = {0.f, 0.f, 0.f, 0.f};
    f32x4 acc2 = {0.f, 0.f, 0.f, 0.f}, acc3 = {0.f, 0.f, 0.f, 0.f};
#pragma unroll
    for (int kk = 0; kk < 8; kk++) {
        short8 af = *(const short8*)(A + kk * 32);
        short8 b0 = *(const short8*)(B + (size_t)(0 * 16 + m) * 256 + kk * 32 + quad * 8);
        short8 b1v = *(const short8*)(B + (size_t)(1 * 16 + m) * 256 + kk * 32 + quad * 8);
        short8 b2v = *(const short8*)(B + (size_t)(2 * 16 + m) * 256 + kk * 32 + quad * 8);
        short8 b3v = *(const short8*)(B + (size_t)(3 * 16 + m) * 256 + kk * 32 + quad * 8);
        acc0 = __builtin_amdgcn_mfma_f32_16x16x32_bf16(af, b0, acc0, 0, 0, 0);
        acc1 = __builtin_amdgcn_mfma_f32_16x16x32_bf16(af, b1v, acc1, 0, 0, 0);
        acc2 = __builtin_amdgcn_mfma_f32_16x16x32_bf16(af, b2v, acc2, 0, 0, 0);
        acc3 = __builtin_amdgcn_mfma_f32_16x16x32_bf16(af, b3v, acc3, 0, 0, 0);
    }
    f32x4 accs[4] = {acc0, acc1, acc2, acc3};

    float vals[4][4];
#pragma unroll
    for (int cb = 0; cb < 4; cb++) {
        float bv = b2[cb * 16 + m];
#pragma unroll
        for (int r = 0; r < 4; r++)
            vals[cb][r] = fmaxf(0.25f * accs[cb][r] + bv, 0.f);
    }

    bool fast = (nodeBase + 15 < N);
    int g0 = 0;
    if (fast) {
        g0 = batch[nodeBase];
        int g1 = batch[nodeBase + 15];
        fast = (g0 == g1);
    }
    if (fast) {
#pragma unroll
        for (int cb = 0; cb < 4; cb++) {
            float s = vals[cb][0] + vals[cb][1] + vals[cb][2] + vals[cb][3];
            s += __shfl_xor(s, 16);
            s += __shfl_xor(s, 32);
            if (quad == 0) atomicAdd(&out[g0 * 64 + cb * 16 + m], s);
        }
    } else {
#pragma unroll
        for (int r = 0; r < 4; r++) {
            int node = nodeBase + quad * 4 + r;
            if (node < N) {
                int g = batch[node];
#pragma unroll
                for (int cb = 0; cb < 4; cb++)
                    atomicAdd(&out[g * 64 + cb * 16 + m], vals[cb][r]);
            }
        }
    }
}

extern "C" void kernel_launch(void* const* d_in, const int* in_sizes, int n_in,
                              void* d_out, int out_size, void* d_ws, size_t ws_size,
                              hipStream_t stream) {
    const float* x   = (const float*)d_in[0];
    const int*   ei  = (const int*)d_in[1];
    const int*   bat = (const int*)d_in[2];
    const float* W1  = (const float*)d_in[3];
    const float* as1 = (const float*)d_in[4];
    const float* ad1 = (const float*)d_in[5];
    const float* b1  = (const float*)d_in[6];
    const float* W2  = (const float*)d_in[7];
    const float* as2 = (const float*)d_in[8];
    const float* ad2 = (const float*)d_in[9];
    const float* b2  = (const float*)d_in[10];
    float* out = (float*)d_out;

    int N = in_sizes[0] / 3;
    int E = in_sizes[1] / 2;
    int G = out_size / 64;
    const int* srcI = ei;
    const int* dstI = ei + E;
    int NBUCK = (N + BWIDTH - 1) >> BSHIFT;

    // ---- workspace layout ----
    float* fw = (float*)d_ws;
    size_t fo = 0;
    unsigned short* aggb = (unsigned short*)fw; fo += (size_t)N * 128;
    unsigned short* houtb = (unsigned short*)(fw + fo); fo += (size_t)N * 32;
    float* esB   = fw + fo; fo += (size_t)N * 4;
    float* edB   = fw + fo; fo += (size_t)N * 4;
    float* p1s   = fw + fo; fo += 64;
    float* p1d   = fw + fo; fo += 64;
    float* qs    = fw + fo; fo += 256;
    float* qd    = fw + fo; fo += 256;
    unsigned short* W2bt = (unsigned short*)(fw + fo); fo += 64 * 256 / 2;
    int* iw = (int*)(fw + fo);
    size_t io = 0;
    unsigned* pairs = (unsigned*)iw; io += E;
    int* csr    = iw + io; io += E;
    int* off    = iw + io; io += N + 1;
    int* bbase  = iw + io; io += 1025;
    int* gcur   = iw + io; io += 1024;
    int* bcnt   = iw + io; io += 1024;

    int nGrpBlk = (N + 15) / 16;

    // ---- CSR build: two-level counting sort ----
    hipMemsetAsync(bcnt, 0, 1024 * sizeof(int), stream);
    k_bhist<<<256, 256, 0, stream>>>(dstI, bcnt, E, NBUCK);
    k_bscan<<<1, 1024, 0, stream>>>(bcnt, bbase, gcur, off, NBUCK, N, E);
    k_bdist<<<(E + DCHUNK - 1) / DCHUNK, 1024, 0, stream>>>(srcI, dstI, gcur, pairs, E, NBUCK);
    k_bcsr<<<NBUCK, 256, 0, stream>>>(pairs, bbase, off, csr, N);

    // ---- fused prep (W1/W2 projections, W2 bf16 transpose, out zero) ----
    k_prep_all<<<198, 256, 0, stream>>>(W1, as1, ad1, W2, as2, ad2,
                                        p1s, p1d, qs, qd, W2bt, out, G * 64);

    // ---- layer 1 (es computed inline from x) ----
    k_agg1<<<nGrpBlk, 256, 0, stream>>>(off, csr, x, p1s, p1d, W1, b1, qs, qd,
                                        houtb, esB, edB, N);

    // ---- layer 2 ----
    k_agg2<<<nGrpBlk, 256, 0, stream>>>(off, csr, esB, edB, houtb, aggb, N);
    k_out2<<<(N + 63) / 64, 256, 0, stream>>>(aggb, W2bt, b2, bat, out, N);
}

// Round 15
// 238.657 us; speedup vs baseline: 1.0383x; 1.0383x over previous
//
#include <hip/hip_runtime.h>
#include <math.h>

#define HEADS 4
#define HID 64
#define BSHIFT 7          // 128 nodes per bucket
#define BWIDTH 128
#define CCAP 4096         // LDS csr-staging capacity (edges/bucket mean ~2047)
#define DCHUNK 8192       // edges per k_bdist block (8 per thread, 1024 threads)
#define APAD 264          // aggl row stride in ushorts (256 + 8 pad -> bank-friendly)

typedef __attribute__((ext_vector_type(8))) short short8;
typedef __attribute__((ext_vector_type(4))) float f32x4;
typedef __attribute__((ext_vector_type(2))) float f32x2;

__device__ __forceinline__ float lrelu(float x) { return x > 0.f ? x : 0.2f * x; }

__device__ __forceinline__ unsigned short bf16r(float f) {
    unsigned u = __float_as_uint(f);
    unsigned r = (u + 0x7FFFu + ((u >> 16) & 1u)) >> 16;
    return (unsigned short)r;
}
__device__ __forceinline__ f32x2 unpk(unsigned u) {
    f32x2 r;
    r.x = __uint_as_float(u << 16);
    r.y = __uint_as_float(u & 0xffff0000u);
    return r;
}

__device__ __forceinline__ float wred_sum(float v) {
#pragma unroll
    for (int o = 32; o > 0; o >>= 1) v += __shfl_xor(v, o);
    return v;
}
__device__ __forceinline__ float red16_sum(float v) {
#pragma unroll
    for (int o = 8; o > 0; o >>= 1) v += __shfl_xor(v, o);
    return v;
}

// ======================= CSR build: two-level LDS counting sort =======================
__global__ void k_bhist(const int* __restrict__ dstI, int* __restrict__ bcnt,
                        int E, int NBUCK) {
    __shared__ int h[1024];
    for (int i = threadIdx.x; i < NBUCK; i += 256) h[i] = 0;
    __syncthreads();
    int stride = gridDim.x * 256;
    for (int e = blockIdx.x * 256 + threadIdx.x; e < E; e += stride)
        atomicAdd(&h[dstI[e] >> BSHIFT], 1);
    __syncthreads();
    for (int i = threadIdx.x; i < NBUCK; i += 256)
        if (h[i]) atomicAdd(&bcnt[i], h[i]);
}

__global__ void k_bscan(const int* __restrict__ bcnt, int* __restrict__ bbase,
                        int* __restrict__ gcur, int* __restrict__ off,
                        int NBUCK, int N, int E) {
    __shared__ int lds[1024];
    int t = threadIdx.x;
    int v = (t < NBUCK) ? bcnt[t] : 0;
    lds[t] = v;
    __syncthreads();
    for (int s = 1; s < 1024; s <<= 1) {
        int u = (t >= s) ? lds[t - s] : 0;
        __syncthreads();
        lds[t] += u;
        __syncthreads();
    }
    if (t < NBUCK) {
        int b = lds[t] - v;
        bbase[t] = b;
        gcur[t] = b;
    }
    if (t == 0) { bbase[NBUCK] = E; off[N] = E; }
}

__global__ void k_bdist(const int* __restrict__ srcI, const int* __restrict__ dstI,
                        int* __restrict__ gcur, unsigned* __restrict__ pairs,
                        int E, int NBUCK) {
    __shared__ int h[1024];
    __shared__ int cur[1024];
    for (int i = threadIdx.x; i < NBUCK; i += 1024) h[i] = 0;
    __syncthreads();
    int base = blockIdx.x * DCHUNK;
    int sr[8], dr[8];
#pragma unroll
    for (int k = 0; k < 8; k++) {
        int e = base + threadIdx.x + k * 1024;
        if (e < E) {
            sr[k] = srcI[e];
            dr[k] = dstI[e];
            atomicAdd(&h[dr[k] >> BSHIFT], 1);
        } else dr[k] = -1;
    }
    __syncthreads();
    for (int i = threadIdx.x; i < NBUCK; i += 1024)
        cur[i] = h[i] ? atomicAdd(&gcur[i], h[i]) : 0;
    __syncthreads();
#pragma unroll
    for (int k = 0; k < 8; k++) {
        if (dr[k] >= 0) {
            int b = dr[k] >> BSHIFT;
            int p = atomicAdd(&cur[b], 1);
            pairs[p] = ((unsigned)sr[k] << BSHIFT) | ((unsigned)dr[k] & (BWIDTH - 1));
        }
    }
}

__global__ void k_bcsr(const unsigned* __restrict__ pairs, const int* __restrict__ bbase,
                       int* __restrict__ off, int* __restrict__ csr, int N) {
    __shared__ int cnt[BWIDTH];
    __shared__ int scan[BWIDTH];
    __shared__ int cur[BWIDTH];
    __shared__ int stage[CCAP];
    int b = blockIdx.x;
    int nodeBase = b << BSHIFT;
    int nNodes = N - nodeBase;
    if (nNodes > BWIDTH) nNodes = BWIDTH;
    int e0 = bbase[b], e1 = bbase[b + 1];
    int ecnt = e1 - e0;
    if (threadIdx.x < BWIDTH) cnt[threadIdx.x] = 0;
    __syncthreads();
    for (int i = threadIdx.x; i < ecnt; i += 256)
        atomicAdd(&cnt[pairs[e0 + i] & (BWIDTH - 1)], 1);
    __syncthreads();
    if (threadIdx.x < BWIDTH)
        scan[threadIdx.x] = (threadIdx.x < nNodes) ? cnt[threadIdx.x] : 0;
    __syncthreads();
    for (int s = 1; s < BWIDTH; s <<= 1) {
        int u = 0;
        if (threadIdx.x < BWIDTH && threadIdx.x >= s) u = scan[threadIdx.x - s];
        __syncthreads();
        if (threadIdx.x < BWIDTH) scan[threadIdx.x] += u;
        __syncthreads();
    }
    if (threadIdx.x < nNodes) {
        int ex = scan[threadIdx.x] - cnt[threadIdx.x];
        off[nodeBase + threadIdx.x] = e0 + ex;
        cur[threadIdx.x] = ex;
    }
    __syncthreads();
    for (int i = threadIdx.x; i < ecnt; i += 256) {
        unsigned pr = pairs[e0 + i];
        int l = atomicAdd(&cur[pr & (BWIDTH - 1)], 1);
        int src = (int)(pr >> BSHIFT);
        if (l < CCAP) stage[l] = src;
        else csr[e0 + l] = src;
    }
    __syncthreads();
    int lim = ecnt < CCAP ? ecnt : CCAP;
    for (int i = threadIdx.x; i < lim; i += 256) csr[e0 + i] = stage[i];
}

// ======================= fused prep: W1-proj, W2-proj, W2->bf16, out-zero =======================
__device__ __forceinline__ void prep_body(const float* __restrict__ W,
                                          const float* __restrict__ asrc,
                                          const float* __restrict__ adst,
                                          float* __restrict__ p_src,
                                          float* __restrict__ p_dst, int K, int blk) {
    int wid = blk * 4 + (threadIdx.x >> 6);
    int lane = threadIdx.x & 63;
    int total = K * 4 * 2;
    if (wid >= total) return;
    int which = wid / (K * 4);
    int hk = wid % (K * 4);
    int h = hk / K, k = hk % K;
    const float* a = which ? adst : asrc;
    float v = W[(size_t)k * 256 + h * 64 + lane] * a[h * 64 + lane];
    v = wred_sum(v);
    if (lane == 0) (which ? p_dst : p_src)[h * K + k] = v;
}

// blocks [0,6): W1 proj; [6,134): W2 proj; [134,198): W2->bf16 transpose + out zero
__global__ void k_prep_all(const float* __restrict__ W1, const float* __restrict__ as1,
                           const float* __restrict__ ad1, const float* __restrict__ W2,
                           const float* __restrict__ as2, const float* __restrict__ ad2,
                           float* __restrict__ p1s, float* __restrict__ p1d,
                           float* __restrict__ qs, float* __restrict__ qd,
                           unsigned short* __restrict__ W2bt, float* __restrict__ out,
                           int outTotal) {
    int b = blockIdx.x;
    if (b < 6) {
        prep_body(W1, as1, ad1, p1s, p1d, 3, b);
    } else if (b < 134) {
        prep_body(W2, as2, ad2, qs, qd, 64, b - 6);
    } else {
        int i = (b - 134) * 256 + threadIdx.x;
        int c = i >> 8, kh = i & 255;
        int h = kh >> 6, kf = kh & 63;
        W2bt[i] = bf16r(W2[kf * 256 + h * 64 + c]);
        if (i < outTotal) out[i] = 0.f;
    }
}

// ======================= layer 1: 16-lane group per node, single pass =======================
__global__ void k_agg1(const int* __restrict__ off, const int* __restrict__ csr,
                       const float* __restrict__ x, const float* __restrict__ ps,
                       const float* __restrict__ pd, const float* __restrict__ W1,
                       const float* __restrict__ b1, const float* __restrict__ qs,
                       const float* __restrict__ qd, unsigned short* __restrict__ houtb,
                       float* __restrict__ es2, float* __restrict__ ed2, int N) {
    int grp = (blockIdx.x * blockDim.x + threadIdx.x) >> 4;
    int l = threadIdx.x & 15;
    int wid = grp;
    bool active = wid < N;
    int o0 = 0, deg = 0;
    float ed0 = 0.f, ed1 = 0.f, ed2v = 0.f, ed3 = 0.f;
    if (active) {
        o0 = off[wid];
        deg = off[wid + 1] - o0;
        float y0 = x[wid * 3], y1 = x[wid * 3 + 1], y2 = x[wid * 3 + 2];
        ed0 = y0 * pd[0] + y1 * pd[1] + y2 * pd[2];
        ed1 = y0 * pd[3] + y1 * pd[4] + y2 * pd[5];
        ed2v = y0 * pd[6] + y1 * pd[7] + y2 * pd[8];
        ed3 = y0 * pd[9] + y1 * pd[10] + y2 * pd[11];
    }

    float t0 = 0.f, t1 = 0.f, t2 = 0.f, t3 = 0.f;
    float a00 = 0, a01 = 0, a02 = 0, a10 = 0, a11 = 0, a12 = 0;
    float a20 = 0, a21 = 0, a22 = 0, a30 = 0, a31 = 0, a32 = 0;
    for (int j = l; j < deg; j += 16) {
        int s = csr[o0 + j];
        float xv0 = x[s * 3], xv1 = x[s * 3 + 1], xv2 = x[s * 3 + 2];
        float e0 = __expf(lrelu(xv0 * ps[0] + xv1 * ps[1] + xv2 * ps[2] + ed0));
        float e1 = __expf(lrelu(xv0 * ps[3] + xv1 * ps[4] + xv2 * ps[5] + ed1));
        float e2 = __expf(lrelu(xv0 * ps[6] + xv1 * ps[7] + xv2 * ps[8] + ed2v));
        float e3 = __expf(lrelu(xv0 * ps[9] + xv1 * ps[10] + xv2 * ps[11] + ed3));
        t0 += e0; t1 += e1; t2 += e2; t3 += e3;
        a00 += e0 * xv0; a01 += e0 * xv1; a02 += e0 * xv2;
        a10 += e1 * xv0; a11 += e1 * xv1; a12 += e1 * xv2;
        a20 += e2 * xv0; a21 += e2 * xv1; a22 += e2 * xv2;
        a30 += e3 * xv0; a31 += e3 * xv1; a32 += e3 * xv2;
    }
    t0 = red16_sum(t0); t1 = red16_sum(t1); t2 = red16_sum(t2); t3 = red16_sum(t3);
    float i0 = t0 > 0.f ? 1.f / t0 : 0.f;
    float i1 = t1 > 0.f ? 1.f / t1 : 0.f;
    float i2 = t2 > 0.f ? 1.f / t2 : 0.f;
    float i3 = t3 > 0.f ? 1.f / t3 : 0.f;
    a00 = red16_sum(a00) * i0; a01 = red16_sum(a01) * i0; a02 = red16_sum(a02) * i0;
    a10 = red16_sum(a10) * i1; a11 = red16_sum(a11) * i1; a12 = red16_sum(a12) * i1;
    a20 = red16_sum(a20) * i2; a21 = red16_sum(a21) * i2; a22 = red16_sum(a22) * i2;
    a30 = red16_sum(a30) * i3; a31 = red16_sum(a31) * i3; a32 = red16_sum(a32) * i3;

    if (!active) return;

    const float4* W1f = (const float4*)W1;
    float4 r = make_float4(0.f, 0.f, 0.f, 0.f);
    float ah[4][3] = {{a00, a01, a02}, {a10, a11, a12}, {a20, a21, a22}, {a30, a31, a32}};
#pragma unroll
    for (int k = 0; k < 3; k++) {
#pragma unroll
        for (int h = 0; h < 4; h++) {
            float4 wv = W1f[k * 64 + h * 16 + l];
            float a = ah[h][k];
            r.x += a * wv.x; r.y += a * wv.y; r.z += a * wv.z; r.w += a * wv.w;
        }
    }
    float4 bv = ((const float4*)b1)[l];
    float4 hv;
    hv.x = fmaxf(0.25f * r.x + bv.x, 0.f);
    hv.y = fmaxf(0.25f * r.y + bv.y, 0.f);
    hv.z = fmaxf(0.25f * r.z + bv.z, 0.f);
    hv.w = fmaxf(0.25f * r.w + bv.w, 0.f);
    ((ushort4*)houtb)[(size_t)wid * 16 + l] =
        make_ushort4(bf16r(hv.x), bf16r(hv.y), bf16r(hv.z), bf16r(hv.w));

    const float4* qsf = (const float4*)qs;
    const float4* qdf = (const float4*)qd;
    float psv[4], pdv[4];
#pragma unroll
    for (int h = 0; h < 4; h++) {
        float4 q = qsf[h * 16 + l];
        psv[h] = red16_sum(hv.x * q.x + hv.y * q.y + hv.z * q.z + hv.w * q.w);
        float4 p = qdf[h * 16 + l];
        pdv[h] = red16_sum(hv.x * p.x + hv.y * p.y + hv.z * p.z + hv.w * p.w);
    }
    if (l == 0) {
        ((float4*)es2)[wid] = make_float4(psv[0], psv[1], psv[2], psv[3]);
        ((float4*)ed2)[wid] = make_float4(pdv[0], pdv[1], pdv[2], pdv[3]);
    }
}

// ======================= layer 2: softmax + gather + fused MFMA transform + pool =======================
// Block = 16 nodes = one 16x16 MFMA tile. Phase A: per-node softmax sums.
// Phase B: packed f32x2 gather of hout -> bf16 agg staged in padded LDS.
// Epilogue: wave 0 runs the 256-deep MFMA transform + bias/relu + pooled atomics.
#define NS 16
__global__ void k_agg2(const int* __restrict__ off, const int* __restrict__ csr,
                       const float* __restrict__ es, const float* __restrict__ ed,
                       const unsigned short* __restrict__ houtb,
                       const unsigned short* __restrict__ W2bt,
                       const float* __restrict__ b2, const int* __restrict__ batch,
                       float* __restrict__ out, int N) {
    __shared__ float exl[NS * 64 * 4];          // 16 KB
    __shared__ int   sl[NS * 64];               // 4 KB
    __shared__ float minv[NS * 4];
    __shared__ int   meta[NS * 2];
    __shared__ unsigned short aggl[NS * APAD];  // 8.25 KB, padded rows

    int l = threadIdx.x & 15;
    int slot = threadIdx.x >> 4;
    int wid = blockIdx.x * NS + slot;
    bool active = wid < N;
    int o0 = 0, deg = 0;
    float4 edv = make_float4(0.f, 0.f, 0.f, 0.f);
    if (active) {
        o0 = off[wid];
        deg = off[wid + 1] - o0;
        edv = ((const float4*)ed)[wid];
    }

    // phase A: exp (no max) -> LDS (first 64 edges) + sum
    float t0 = 0.f, t1 = 0.f, t2 = 0.f, t3 = 0.f;
    for (int j = l; j < deg; j += 16) {
        int s = csr[o0 + j];
        float4 ev = ((const float4*)es)[s];
        float e0 = __expf(lrelu(ev.x + edv.x));
        float e1 = __expf(lrelu(ev.y + edv.y));
        float e2 = __expf(lrelu(ev.z + edv.z));
        float e3 = __expf(lrelu(ev.w + edv.w));
        if (j < 64) {
            ((float4*)exl)[slot * 64 + j] = make_float4(e0, e1, e2, e3);
            sl[slot * 64 + j] = s;
        }
        t0 += e0; t1 += e1; t2 += e2; t3 += e3;
    }
    {
        int dmain = deg < 64 ? deg : 64;
        int d8 = (dmain + 7) & ~7;
        if (dmain + l < d8) {
            ((float4*)exl)[slot * 64 + dmain + l] = make_float4(0.f, 0.f, 0.f, 0.f);
            sl[slot * 64 + dmain + l] = 0;
        }
    }
    // zero agg rows of inactive slots so MFMA reads are finite (outputs discarded anyway)
    if (!active) {
        for (int i = l; i < 128; i += 16)
            ((unsigned*)(aggl + slot * APAD))[i] = 0u;
    }
    t0 = red16_sum(t0); t1 = red16_sum(t1); t2 = red16_sum(t2); t3 = red16_sum(t3);
    if (l == 0) {
        minv[slot * 4 + 0] = t0 > 0.f ? 1.f / t0 : 0.f;
        minv[slot * 4 + 1] = t1 > 0.f ? 1.f / t1 : 0.f;
        minv[slot * 4 + 2] = t2 > 0.f ? 1.f / t2 : 0.f;
        minv[slot * 4 + 3] = t3 > 0.f ? 1.f / t3 : 0.f;
        meta[slot * 2 + 0] = o0;
        meta[slot * 2 + 1] = deg;
    }
    __syncthreads();

    int lane = threadIdx.x & 63;
    int w = threadIdx.x >> 6;
    int half = lane >> 5;
    int c2 = lane & 31;
    for (int sidx = 0; sidx < 4; sidx++) {
        int slot2 = w * 4 + sidx;
        int nd = blockIdx.x * NS + slot2;
        if (nd >= N) continue;
        int o0b = meta[slot2 * 2 + 0], degb = meta[slot2 * 2 + 1];
        float iv0 = minv[slot2 * 4 + 0], iv1 = minv[slot2 * 4 + 1];
        float iv2 = minv[slot2 * 4 + 2], iv3 = minv[slot2 * 4 + 3];

        f32x2 q0 = {0.f, 0.f}, q1 = {0.f, 0.f}, q2 = {0.f, 0.f}, q3 = {0.f, 0.f};
        const float4* EX = ((const float4*)exl) + slot2 * 64;
        const int* S = sl + slot2 * 64;
        int dmain = degb < 64 ? degb : 64;
        int d8 = (dmain + 7) & ~7;
        for (int j = 0; j < d8; j += 8) {
            float4 a0 = EX[j + half];
            float4 a1 = EX[j + 2 + half];
            float4 a2 = EX[j + 4 + half];
            float4 a3 = EX[j + 6 + half];
            int s0 = S[j + half], s1 = S[j + 2 + half];
            int s2 = S[j + 4 + half], s3 = S[j + 6 + half];
            unsigned u0 = *(const unsigned*)(houtb + (size_t)s0 * 64 + 2 * c2);
            unsigned u1 = *(const unsigned*)(houtb + (size_t)s1 * 64 + 2 * c2);
            unsigned u2 = *(const unsigned*)(houtb + (size_t)s2 * 64 + 2 * c2);
            unsigned u3 = *(const unsigned*)(houtb + (size_t)s3 * 64 + 2 * c2);
            f32x2 v0 = unpk(u0), v1 = unpk(u1), v2 = unpk(u2), v3 = unpk(u3);
            q0 += a0.x * v0; q0 += a1.x * v1; q0 += a2.x * v2; q0 += a3.x * v3;
            q1 += a0.y * v0; q1 += a1.y * v1; q1 += a2.y * v2; q1 += a3.y * v3;
            q2 += a0.z * v0; q2 += a1.z * v1; q2 += a2.z * v2; q2 += a3.z * v3;
            q3 += a0.w * v0; q3 += a1.w * v1; q3 += a2.w * v2; q3 += a3.w * v3;
        }
        if (degb > 64) {
            float4 edv2 = ((const float4*)ed)[nd];
            for (int j = 64 + half; j < degb; j += 2) {
                int s = csr[o0b + j];
                float4 ev = ((const float4*)es)[s];
                float e0 = __expf(lrelu(ev.x + edv2.x));
                float e1 = __expf(lrelu(ev.y + edv2.y));
                float e2 = __expf(lrelu(ev.z + edv2.z));
                float e3 = __expf(lrelu(ev.w + edv2.w));
                unsigned u = *(const unsigned*)(houtb + (size_t)s * 64 + 2 * c2);
                f32x2 v = unpk(u);
                q0 += e0 * v; q1 += e1 * v; q2 += e2 * v; q3 += e3 * v;
            }
        }
        q0.x += __shfl_xor(q0.x, 32); q0.y += __shfl_xor(q0.y, 32);
        q1.x += __shfl_xor(q1.x, 32); q1.y += __shfl_xor(q1.y, 32);
        q2.x += __shfl_xor(q2.x, 32); q2.y += __shfl_xor(q2.y, 32);
        q3.x += __shfl_xor(q3.x, 32); q3.y += __shfl_xor(q3.y, 32);

        if (half == 0) {
            unsigned short* arow = aggl + slot2 * APAD;
            unsigned w0 = (unsigned)bf16r(q0.x * iv0) | ((unsigned)bf16r(q0.y * iv0) << 16);
            unsigned w1 = (unsigned)bf16r(q1.x * iv1) | ((unsigned)bf16r(q1.y * iv1) << 16);
            unsigned w2 = (unsigned)bf16r(q2.x * iv2) | ((unsigned)bf16r(q2.y * iv2) << 16);
            unsigned w3 = (unsigned)bf16r(q3.x * iv3) | ((unsigned)bf16r(q3.y * iv3) << 16);
            *(unsigned*)(arow + 2 * c2)        = w0;
            *(unsigned*)(arow + 64 + 2 * c2)   = w1;
            *(unsigned*)(arow + 128 + 2 * c2)  = w2;
            *(unsigned*)(arow + 192 + 2 * c2)  = w3;
        }
    }
    __syncthreads();

    // ---- epilogue (wave 0 only): MFMA transform + bias/relu + pooled atomics ----
    if (w != 0) return;
    int nodeBase = blockIdx.x * NS;
    int m = lane & 15;
    int quad = lane >> 4;
    const short* A = (const short*)aggl + m * APAD + quad * 8;
    const short* B = (const short*)W2bt;

    f32x4 acc0 = {0.f, 0.f, 0.f, 0.f}, acc1 = {0.f, 0.f, 0.f, 0.f};
    f32x4 acc2 = {0.f, 0.f, 0.f, 0.f}, acc3 = {0.f, 0.f, 0.f, 0.f};
#pragma unroll
    for (int kk = 0; kk < 8; kk++) {
        short8 af = *(const short8*)(A + kk * 32);
        short8 b0 = *(const short8*)(B + (size_t)(0 * 16 + m) * 256 + kk * 32 + quad * 8);
        short8 b1v = *(const short8*)(B + (size_t)(1 * 16 + m) * 256 + kk * 32 + quad * 8);
        short8 b2v = *(const short8*)(B + (size_t)(2 * 16 + m) * 256 + kk * 32 + quad * 8);
        short8 b3v = *(const short8*)(B + (size_t)(3 * 16 + m) * 256 + kk * 32 + quad * 8);
        acc0 = __builtin_amdgcn_mfma_f32_16x16x32_bf16(af, b0, acc0, 0, 0, 0);
        acc1 = __builtin_amdgcn_mfma_f32_16x16x32_bf16(af, b1v, acc1, 0, 0, 0);
        acc2 = __builtin_amdgcn_mfma_f32_16x16x32_bf16(af, b2v, acc2, 0, 0, 0);
        acc3 = __builtin_amdgcn_mfma_f32_16x16x32_bf16(af, b3v, acc3, 0, 0, 0);
    }
    f32x4 accs[4] = {acc0, acc1, acc2, acc3};

    float vals[4][4];
#pragma unroll
    for (int cb = 0; cb < 4; cb++) {
        float bv = b2[cb * 16 + m];
#pragma unroll
        for (int r = 0; r < 4; r++)
            vals[cb][r] = fmaxf(0.25f * accs[cb][r] + bv, 0.f);
    }

    bool fast = (nodeBase + 15 < N);
    int g0 = 0;
    if (fast) {
        g0 = batch[nodeBase];
        int g1 = batch[nodeBase + 15];
        fast = (g0 == g1);
    }
    if (fast) {
#pragma unroll
        for (int cb = 0; cb < 4; cb++) {
            float s = vals[cb][0] + vals[cb][1] + vals[cb][2] + vals[cb][3];
            s += __shfl_xor(s, 16);
            s += __shfl_xor(s, 32);
            if (quad == 0) atomicAdd(&out[g0 * 64 + cb * 16 + m], s);
        }
    } else {
#pragma unroll
        for (int r = 0; r < 4; r++) {
            int node = nodeBase + quad * 4 + r;
            if (node < N) {
                int g = batch[node];
#pragma unroll
                for (int cb = 0; cb < 4; cb++)
                    atomicAdd(&out[g * 64 + cb * 16 + m], vals[cb][r]);
            }
        }
    }
}

extern "C" void kernel_launch(void* const* d_in, const int* in_sizes, int n_in,
                              void* d_out, int out_size, void* d_ws, size_t ws_size,
                              hipStream_t stream) {
    const float* x   = (const float*)d_in[0];
    const int*   ei  = (const int*)d_in[1];
    const int*   bat = (const int*)d_in[2];
    const float* W1  = (const float*)d_in[3];
    const float* as1 = (const float*)d_in[4];
    const float* ad1 = (const float*)d_in[5];
    const float* b1  = (const float*)d_in[6];
    const float* W2  = (const float*)d_in[7];
    const float* as2 = (const float*)d_in[8];
    const float* ad2 = (const float*)d_in[9];
    const float* b2  = (const float*)d_in[10];
    float* out = (float*)d_out;

    int N = in_sizes[0] / 3;
    int E = in_sizes[1] / 2;
    int G = out_size / 64;
    const int* srcI = ei;
    const int* dstI = ei + E;
    int NBUCK = (N + BWIDTH - 1) >> BSHIFT;

    // ---- workspace layout ----
    float* fw = (float*)d_ws;
    size_t fo = 0;
    unsigned short* houtb = (unsigned short*)fw; fo += (size_t)N * 32;
    float* esB   = fw + fo; fo += (size_t)N * 4;
    float* edB   = fw + fo; fo += (size_t)N * 4;
    float* p1s   = fw + fo; fo += 64;
    float* p1d   = fw + fo; fo += 64;
    float* qs    = fw + fo; fo += 256;
    float* qd    = fw + fo; fo += 256;
    unsigned short* W2bt = (unsigned short*)(fw + fo); fo += 64 * 256 / 2;
    int* iw = (int*)(fw + fo);
    size_t io = 0;
    unsigned* pairs = (unsigned*)iw; io += E;
    int* csr    = iw + io; io += E;
    int* off    = iw + io; io += N + 1;
    int* bbase  = iw + io; io += 1025;
    int* gcur   = iw + io; io += 1024;
    int* bcnt   = iw + io; io += 1024;

    int nGrpBlk = (N + 15) / 16;

    // ---- CSR build: two-level counting sort ----
    hipMemsetAsync(bcnt, 0, 1024 * sizeof(int), stream);
    k_bhist<<<256, 256, 0, stream>>>(dstI, bcnt, E, NBUCK);
    k_bscan<<<1, 1024, 0, stream>>>(bcnt, bbase, gcur, off, NBUCK, N, E);
    k_bdist<<<(E + DCHUNK - 1) / DCHUNK, 1024, 0, stream>>>(srcI, dstI, gcur, pairs, E, NBUCK);
    k_bcsr<<<NBUCK, 256, 0, stream>>>(pairs, bbase, off, csr, N);

    // ---- fused prep (W1/W2 projections, W2 bf16 transpose, out zero) ----
    k_prep_all<<<198, 256, 0, stream>>>(W1, as1, ad1, W2, as2, ad2,
                                        p1s, p1d, qs, qd, W2bt, out, G * 64);

    // ---- layer 1 ----
    k_agg1<<<nGrpBlk, 256, 0, stream>>>(off, csr, x, p1s, p1d, W1, b1, qs, qd,
                                        houtb, esB, edB, N);

    // ---- layer 2 (aggregate + fused MFMA transform + pool) ----
    k_agg2<<<nGrpBlk, 256, 0, stream>>>(off, csr, esB, edB, houtb, W2bt, b2, bat, out, N);
}

// Round 16
// 229.986 us; speedup vs baseline: 1.0775x; 1.0377x over previous
//
#include <hip/hip_runtime.h>
#include <math.h>

#define HEADS 4
#define HID 64
#define BSHIFT 7          // 128 nodes per bucket
#define BWIDTH 128
#define CCAP 4096         // LDS csr-staging capacity (edges/bucket mean ~2047)
#define DCHUNK 8192       // edges per k_bdist block (8 per thread, 1024 threads)
#define APAD 264          // aggl row stride in ushorts (256 + 8 pad)

typedef __attribute__((ext_vector_type(8))) short short8;
typedef __attribute__((ext_vector_type(4))) float f32x4;
typedef __attribute__((ext_vector_type(2))) float f32x2;

__device__ __forceinline__ float lrelu(float x) { return x > 0.f ? x : 0.2f * x; }

__device__ __forceinline__ unsigned short bf16r(float f) {
    unsigned u = __float_as_uint(f);
    unsigned r = (u + 0x7FFFu + ((u >> 16) & 1u)) >> 16;
    return (unsigned short)r;
}
__device__ __forceinline__ unsigned pk2(float a, float b) {
    return (unsigned)bf16r(a) | ((unsigned)bf16r(b) << 16);
}
__device__ __forceinline__ f32x2 unpk(unsigned u) {
    f32x2 r;
    r.x = __uint_as_float(u << 16);
    r.y = __uint_as_float(u & 0xffff0000u);
    return r;
}

__device__ __forceinline__ float wred_sum(float v) {
#pragma unroll
    for (int o = 32; o > 0; o >>= 1) v += __shfl_xor(v, o);
    return v;
}
__device__ __forceinline__ float red16_sum(float v) {
#pragma unroll
    for (int o = 8; o > 0; o >>= 1) v += __shfl_xor(v, o);
    return v;
}

// ======================= CSR build: two-level LDS counting sort =======================
__global__ void k_bhist(const int* __restrict__ dstI, int* __restrict__ bcnt,
                        int E, int NBUCK) {
    __shared__ int h[1024];
    for (int i = threadIdx.x; i < NBUCK; i += 256) h[i] = 0;
    __syncthreads();
    int stride = gridDim.x * 256;
    for (int e = blockIdx.x * 256 + threadIdx.x; e < E; e += stride)
        atomicAdd(&h[dstI[e] >> BSHIFT], 1);
    __syncthreads();
    for (int i = threadIdx.x; i < NBUCK; i += 256)
        if (h[i]) atomicAdd(&bcnt[i], h[i]);
}

__global__ void k_bscan(const int* __restrict__ bcnt, int* __restrict__ bbase,
                        int* __restrict__ gcur, int* __restrict__ off,
                        int NBUCK, int N, int E) {
    __shared__ int lds[1024];
    int t = threadIdx.x;
    int v = (t < NBUCK) ? bcnt[t] : 0;
    lds[t] = v;
    __syncthreads();
    for (int s = 1; s < 1024; s <<= 1) {
        int u = (t >= s) ? lds[t - s] : 0;
        __syncthreads();
        lds[t] += u;
        __syncthreads();
    }
    if (t < NBUCK) {
        int b = lds[t] - v;
        bbase[t] = b;
        gcur[t] = b;
    }
    if (t == 0) { bbase[NBUCK] = E; off[N] = E; }
}

__global__ void k_bdist(const int* __restrict__ srcI, const int* __restrict__ dstI,
                        int* __restrict__ gcur, unsigned* __restrict__ pairs,
                        int E, int NBUCK) {
    __shared__ int h[1024];
    __shared__ int cur[1024];
    for (int i = threadIdx.x; i < NBUCK; i += 1024) h[i] = 0;
    __syncthreads();
    int base = blockIdx.x * DCHUNK;
    int sr[8], dr[8];
#pragma unroll
    for (int k = 0; k < 8; k++) {
        int e = base + threadIdx.x + k * 1024;
        if (e < E) {
            sr[k] = srcI[e];
            dr[k] = dstI[e];
            atomicAdd(&h[dr[k] >> BSHIFT], 1);
        } else dr[k] = -1;
    }
    __syncthreads();
    for (int i = threadIdx.x; i < NBUCK; i += 1024)
        cur[i] = h[i] ? atomicAdd(&gcur[i], h[i]) : 0;
    __syncthreads();
#pragma unroll
    for (int k = 0; k < 8; k++) {
        if (dr[k] >= 0) {
            int b = dr[k] >> BSHIFT;
            int p = atomicAdd(&cur[b], 1);
            pairs[p] = ((unsigned)sr[k] << BSHIFT) | ((unsigned)dr[k] & (BWIDTH - 1));
        }
    }
}

__global__ void k_bcsr(const unsigned* __restrict__ pairs, const int* __restrict__ bbase,
                       int* __restrict__ off, int* __restrict__ csr, int N) {
    __shared__ int cnt[BWIDTH];
    __shared__ int scan[BWIDTH];
    __shared__ int cur[BWIDTH];
    __shared__ int stage[CCAP];
    int b = blockIdx.x;
    int nodeBase = b << BSHIFT;
    int nNodes = N - nodeBase;
    if (nNodes > BWIDTH) nNodes = BWIDTH;
    int e0 = bbase[b], e1 = bbase[b + 1];
    int ecnt = e1 - e0;
    if (threadIdx.x < BWIDTH) cnt[threadIdx.x] = 0;
    __syncthreads();
    for (int i = threadIdx.x; i < ecnt; i += 256)
        atomicAdd(&cnt[pairs[e0 + i] & (BWIDTH - 1)], 1);
    __syncthreads();
    if (threadIdx.x < BWIDTH)
        scan[threadIdx.x] = (threadIdx.x < nNodes) ? cnt[threadIdx.x] : 0;
    __syncthreads();
    for (int s = 1; s < BWIDTH; s <<= 1) {
        int u = 0;
        if (threadIdx.x < BWIDTH && threadIdx.x >= s) u = scan[threadIdx.x - s];
        __syncthreads();
        if (threadIdx.x < BWIDTH) scan[threadIdx.x] += u;
        __syncthreads();
    }
    if (threadIdx.x < nNodes) {
        int ex = scan[threadIdx.x] - cnt[threadIdx.x];
        off[nodeBase + threadIdx.x] = e0 + ex;
        cur[threadIdx.x] = ex;
    }
    __syncthreads();
    for (int i = threadIdx.x; i < ecnt; i += 256) {
        unsigned pr = pairs[e0 + i];
        int l = atomicAdd(&cur[pr & (BWIDTH - 1)], 1);
        int src = (int)(pr >> BSHIFT);
        if (l < CCAP) stage[l] = src;
        else csr[e0 + l] = src;
    }
    __syncthreads();
    int lim = ecnt < CCAP ? ecnt : CCAP;
    for (int i = threadIdx.x; i < lim; i += 256) csr[e0 + i] = stage[i];
}

// ======================= fused prep: W1-proj, W2-proj, W2->bf16, out-zero =======================
__device__ __forceinline__ void prep_body(const float* __restrict__ W,
                                          const float* __restrict__ asrc,
                                          const float* __restrict__ adst,
                                          float* __restrict__ p_src,
                                          float* __restrict__ p_dst, int K, int blk) {
    int wid = blk * 4 + (threadIdx.x >> 6);
    int lane = threadIdx.x & 63;
    int total = K * 4 * 2;
    if (wid >= total) return;
    int which = wid / (K * 4);
    int hk = wid % (K * 4);
    int h = hk / K, k = hk % K;
    const float* a = which ? adst : asrc;
    float v = W[(size_t)k * 256 + h * 64 + lane] * a[h * 64 + lane];
    v = wred_sum(v);
    if (lane == 0) (which ? p_dst : p_src)[h * K + k] = v;
}

__global__ void k_prep_all(const float* __restrict__ W1, const float* __restrict__ as1,
                           const float* __restrict__ ad1, const float* __restrict__ W2,
                           const float* __restrict__ as2, const float* __restrict__ ad2,
                           float* __restrict__ p1s, float* __restrict__ p1d,
                           float* __restrict__ qs, float* __restrict__ qd,
                           unsigned short* __restrict__ W2bt, float* __restrict__ out,
                           int outTotal) {
    int b = blockIdx.x;
    if (b < 6) {
        prep_body(W1, as1, ad1, p1s, p1d, 3, b);
    } else if (b < 134) {
        prep_body(W2, as2, ad2, qs, qd, 64, b - 6);
    } else {
        int i = (b - 134) * 256 + threadIdx.x;
        int c = i >> 8, kh = i & 255;
        int h = kh >> 6, kf = kh & 63;
        W2bt[i] = bf16r(W2[kf * 256 + h * 64 + c]);
        if (i < outTotal) out[i] = 0.f;
    }
}

// ======================= layer 1: 16-lane group per node, single pass =======================
__global__ void k_agg1(const int* __restrict__ off, const int* __restrict__ csr,
                       const float* __restrict__ x, const float* __restrict__ ps,
                       const float* __restrict__ pd, const float* __restrict__ W1,
                       const float* __restrict__ b1, const float* __restrict__ qs,
                       const float* __restrict__ qd, unsigned short* __restrict__ houtb,
                       float* __restrict__ es2, float* __restrict__ ed2, int N) {
    int grp = (blockIdx.x * blockDim.x + threadIdx.x) >> 4;
    int l = threadIdx.x & 15;
    int wid = grp;
    bool active = wid < N;
    int o0 = 0, deg = 0;
    float ed0 = 0.f, ed1 = 0.f, ed2v = 0.f, ed3 = 0.f;
    if (active) {
        o0 = off[wid];
        deg = off[wid + 1] - o0;
        float y0 = x[wid * 3], y1 = x[wid * 3 + 1], y2 = x[wid * 3 + 2];
        ed0 = y0 * pd[0] + y1 * pd[1] + y2 * pd[2];
        ed1 = y0 * pd[3] + y1 * pd[4] + y2 * pd[5];
        ed2v = y0 * pd[6] + y1 * pd[7] + y2 * pd[8];
        ed3 = y0 * pd[9] + y1 * pd[10] + y2 * pd[11];
    }

    float t0 = 0.f, t1 = 0.f, t2 = 0.f, t3 = 0.f;
    float a00 = 0, a01 = 0, a02 = 0, a10 = 0, a11 = 0, a12 = 0;
    float a20 = 0, a21 = 0, a22 = 0, a30 = 0, a31 = 0, a32 = 0;
    for (int j = l; j < deg; j += 16) {
        int s = csr[o0 + j];
        float xv0 = x[s * 3], xv1 = x[s * 3 + 1], xv2 = x[s * 3 + 2];
        float e0 = __expf(lrelu(xv0 * ps[0] + xv1 * ps[1] + xv2 * ps[2] + ed0));
        float e1 = __expf(lrelu(xv0 * ps[3] + xv1 * ps[4] + xv2 * ps[5] + ed1));
        float e2 = __expf(lrelu(xv0 * ps[6] + xv1 * ps[7] + xv2 * ps[8] + ed2v));
        float e3 = __expf(lrelu(xv0 * ps[9] + xv1 * ps[10] + xv2 * ps[11] + ed3));
        t0 += e0; t1 += e1; t2 += e2; t3 += e3;
        a00 += e0 * xv0; a01 += e0 * xv1; a02 += e0 * xv2;
        a10 += e1 * xv0; a11 += e1 * xv1; a12 += e1 * xv2;
        a20 += e2 * xv0; a21 += e2 * xv1; a22 += e2 * xv2;
        a30 += e3 * xv0; a31 += e3 * xv1; a32 += e3 * xv2;
    }
    t0 = red16_sum(t0); t1 = red16_sum(t1); t2 = red16_sum(t2); t3 = red16_sum(t3);
    float i0 = t0 > 0.f ? 1.f / t0 : 0.f;
    float i1 = t1 > 0.f ? 1.f / t1 : 0.f;
    float i2 = t2 > 0.f ? 1.f / t2 : 0.f;
    float i3 = t3 > 0.f ? 1.f / t3 : 0.f;
    a00 = red16_sum(a00) * i0; a01 = red16_sum(a01) * i0; a02 = red16_sum(a02) * i0;
    a10 = red16_sum(a10) * i1; a11 = red16_sum(a11) * i1; a12 = red16_sum(a12) * i1;
    a20 = red16_sum(a20) * i2; a21 = red16_sum(a21) * i2; a22 = red16_sum(a22) * i2;
    a30 = red16_sum(a30) * i3; a31 = red16_sum(a31) * i3; a32 = red16_sum(a32) * i3;

    if (!active) return;

    const float4* W1f = (const float4*)W1;
    float4 r = make_float4(0.f, 0.f, 0.f, 0.f);
    float ah[4][3] = {{a00, a01, a02}, {a10, a11, a12}, {a20, a21, a22}, {a30, a31, a32}};
#pragma unroll
    for (int k = 0; k < 3; k++) {
#pragma unroll
        for (int h = 0; h < 4; h++) {
            float4 wv = W1f[k * 64 + h * 16 + l];
            float a = ah[h][k];
            r.x += a * wv.x; r.y += a * wv.y; r.z += a * wv.z; r.w += a * wv.w;
        }
    }
    float4 bv = ((const float4*)b1)[l];
    float4 hv;
    hv.x = fmaxf(0.25f * r.x + bv.x, 0.f);
    hv.y = fmaxf(0.25f * r.y + bv.y, 0.f);
    hv.z = fmaxf(0.25f * r.z + bv.z, 0.f);
    hv.w = fmaxf(0.25f * r.w + bv.w, 0.f);
    ((ushort4*)houtb)[(size_t)wid * 16 + l] =
        make_ushort4(bf16r(hv.x), bf16r(hv.y), bf16r(hv.z), bf16r(hv.w));

    const float4* qsf = (const float4*)qs;
    const float4* qdf = (const float4*)qd;
    float psv[4], pdv[4];
#pragma unroll
    for (int h = 0; h < 4; h++) {
        float4 q = qsf[h * 16 + l];
        psv[h] = red16_sum(hv.x * q.x + hv.y * q.y + hv.z * q.z + hv.w * q.w);
        float4 p = qdf[h * 16 + l];
        pdv[h] = red16_sum(hv.x * p.x + hv.y * p.y + hv.z * p.z + hv.w * p.w);
    }
    if (l == 0) {
        ((float4*)es2)[wid] = make_float4(psv[0], psv[1], psv[2], psv[3]);
        ((float4*)ed2)[wid] = make_float4(pdv[0], pdv[1], pdv[2], pdv[3]);
    }
}

// ======================= layer 2: softmax + gather + fused MFMA transform + pool =======================
// exl now packed bf16x4 (uint2/edge, 8 KB) -> total LDS ~21 KB, occupancy restored.
#define NS 16
__global__ void k_agg2(const int* __restrict__ off, const int* __restrict__ csr,
                       const float* __restrict__ es, const float* __restrict__ ed,
                       const unsigned short* __restrict__ houtb,
                       const unsigned short* __restrict__ W2bt,
                       const float* __restrict__ b2, const int* __restrict__ batch,
                       float* __restrict__ out, int N) {
    __shared__ unsigned exl[NS * 64 * 2];       // 8 KB: (e0|e1, e2|e3) bf16 packed
    __shared__ int   sl[NS * 64];               // 4 KB
    __shared__ float minv[NS * 4];
    __shared__ int   meta[NS * 2];
    __shared__ unsigned short aggl[NS * APAD];  // 8.25 KB

    int l = threadIdx.x & 15;
    int slot = threadIdx.x >> 4;
    int wid = blockIdx.x * NS + slot;
    bool active = wid < N;
    int o0 = 0, deg = 0;
    float4 edv = make_float4(0.f, 0.f, 0.f, 0.f);
    if (active) {
        o0 = off[wid];
        deg = off[wid + 1] - o0;
        edv = ((const float4*)ed)[wid];
    }

    // phase A: exp (no max) -> packed bf16 LDS (first 64 edges) + fp32 sum
    float t0 = 0.f, t1 = 0.f, t2 = 0.f, t3 = 0.f;
    for (int j = l; j < deg; j += 16) {
        int s = csr[o0 + j];
        float4 ev = ((const float4*)es)[s];
        float e0 = __expf(lrelu(ev.x + edv.x));
        float e1 = __expf(lrelu(ev.y + edv.y));
        float e2 = __expf(lrelu(ev.z + edv.z));
        float e3 = __expf(lrelu(ev.w + edv.w));
        if (j < 64) {
            ((uint2*)exl)[slot * 64 + j] = make_uint2(pk2(e0, e1), pk2(e2, e3));
            sl[slot * 64 + j] = s;
        }
        t0 += e0; t1 += e1; t2 += e2; t3 += e3;
    }
    {
        int dmain = deg < 64 ? deg : 64;
        int d8 = (dmain + 7) & ~7;
        if (dmain + l < d8) {
            ((uint2*)exl)[slot * 64 + dmain + l] = make_uint2(0u, 0u);
            sl[slot * 64 + dmain + l] = 0;
        }
    }
    if (!active) {
        for (int i = l; i < 128; i += 16)
            ((unsigned*)(aggl + slot * APAD))[i] = 0u;
    }
    t0 = red16_sum(t0); t1 = red16_sum(t1); t2 = red16_sum(t2); t3 = red16_sum(t3);
    if (l == 0) {
        minv[slot * 4 + 0] = t0 > 0.f ? 1.f / t0 : 0.f;
        minv[slot * 4 + 1] = t1 > 0.f ? 1.f / t1 : 0.f;
        minv[slot * 4 + 2] = t2 > 0.f ? 1.f / t2 : 0.f;
        minv[slot * 4 + 3] = t3 > 0.f ? 1.f / t3 : 0.f;
        meta[slot * 2 + 0] = o0;
        meta[slot * 2 + 1] = deg;
    }
    __syncthreads();

    int lane = threadIdx.x & 63;
    int w = threadIdx.x >> 6;
    int half = lane >> 5;
    int c2 = lane & 31;
    for (int sidx = 0; sidx < 4; sidx++) {
        int slot2 = w * 4 + sidx;
        int nd = blockIdx.x * NS + slot2;
        if (nd >= N) continue;
        int o0b = meta[slot2 * 2 + 0], degb = meta[slot2 * 2 + 1];
        float iv0 = minv[slot2 * 4 + 0], iv1 = minv[slot2 * 4 + 1];
        float iv2 = minv[slot2 * 4 + 2], iv3 = minv[slot2 * 4 + 3];

        f32x2 q0 = {0.f, 0.f}, q1 = {0.f, 0.f}, q2 = {0.f, 0.f}, q3 = {0.f, 0.f};
        const uint2* EX = ((const uint2*)exl) + slot2 * 64;
        const int* S = sl + slot2 * 64;
        int dmain = degb < 64 ? degb : 64;
        int d8 = (dmain + 7) & ~7;
        for (int j = 0; j < d8; j += 8) {
            uint2 ua = EX[j + half];
            uint2 ub = EX[j + 2 + half];
            uint2 uc = EX[j + 4 + half];
            uint2 ud = EX[j + 6 + half];
            int s0 = S[j + half], s1 = S[j + 2 + half];
            int s2 = S[j + 4 + half], s3 = S[j + 6 + half];
            unsigned u0 = *(const unsigned*)(houtb + (size_t)s0 * 64 + 2 * c2);
            unsigned u1 = *(const unsigned*)(houtb + (size_t)s1 * 64 + 2 * c2);
            unsigned u2 = *(const unsigned*)(houtb + (size_t)s2 * 64 + 2 * c2);
            unsigned u3 = *(const unsigned*)(houtb + (size_t)s3 * 64 + 2 * c2);
            f32x2 v0 = unpk(u0), v1 = unpk(u1), v2 = unpk(u2), v3 = unpk(u3);
            f32x2 a01v = unpk(ua.x), a23v = unpk(ua.y);
            f32x2 b01v = unpk(ub.x), b23v = unpk(ub.y);
            f32x2 c01v = unpk(uc.x), c23v = unpk(uc.y);
            f32x2 d01v = unpk(ud.x), d23v = unpk(ud.y);
            q0 += a01v.x * v0; q0 += b01v.x * v1; q0 += c01v.x * v2; q0 += d01v.x * v3;
            q1 += a01v.y * v0; q1 += b01v.y * v1; q1 += c01v.y * v2; q1 += d01v.y * v3;
            q2 += a23v.x * v0; q2 += b23v.x * v1; q2 += c23v.x * v2; q2 += d23v.x * v3;
            q3 += a23v.y * v0; q3 += b23v.y * v1; q3 += c23v.y * v2; q3 += d23v.y * v3;
        }
        if (degb > 64) {
            float4 edv2 = ((const float4*)ed)[nd];
            for (int j = 64 + half; j < degb; j += 2) {
                int s = csr[o0b + j];
                float4 ev = ((const float4*)es)[s];
                float e0 = __expf(lrelu(ev.x + edv2.x));
                float e1 = __expf(lrelu(ev.y + edv2.y));
                float e2 = __expf(lrelu(ev.z + edv2.z));
                float e3 = __expf(lrelu(ev.w + edv2.w));
                unsigned u = *(const unsigned*)(houtb + (size_t)s * 64 + 2 * c2);
                f32x2 v = unpk(u);
                q0 += e0 * v; q1 += e1 * v; q2 += e2 * v; q3 += e3 * v;
            }
        }
        q0.x += __shfl_xor(q0.x, 32); q0.y += __shfl_xor(q0.y, 32);
        q1.x += __shfl_xor(q1.x, 32); q1.y += __shfl_xor(q1.y, 32);
        q2.x += __shfl_xor(q2.x, 32); q2.y += __shfl_xor(q2.y, 32);
        q3.x += __shfl_xor(q3.x, 32); q3.y += __shfl_xor(q3.y, 32);

        if (half == 0) {
            unsigned short* arow = aggl + slot2 * APAD;
            *(unsigned*)(arow + 2 * c2)        = pk2(q0.x * iv0, q0.y * iv0);
            *(unsigned*)(arow + 64 + 2 * c2)   = pk2(q1.x * iv1, q1.y * iv1);
            *(unsigned*)(arow + 128 + 2 * c2)  = pk2(q2.x * iv2, q2.y * iv2);
            *(unsigned*)(arow + 192 + 2 * c2)  = pk2(q3.x * iv3, q3.y * iv3);
        }
    }
    __syncthreads();

    // ---- epilogue (wave 0 only): MFMA transform + bias/relu + pooled atomics ----
    if (w != 0) return;
    int nodeBase = blockIdx.x * NS;
    int m = lane & 15;
    int quad = lane >> 4;
    const short* A = (const short*)aggl + m * APAD + quad * 8;
    const short* B = (const short*)W2bt;

    f32x4 acc0 = {0.f, 0.f, 0.f, 0.f}, acc1 = {0.f, 0.f, 0.f, 0.f};
    f32x4 acc2 = {0.f, 0.f, 0.f, 0.f}, acc3 = {0.f, 0.f, 0.f, 0.f};
#pragma unroll
    for (int kk = 0; kk < 8; kk++) {
        short8 af = *(const short8*)(A + kk * 32);
        short8 b0 = *(const short8*)(B + (size_t)(0 * 16 + m) * 256 + kk * 32 + quad * 8);
        short8 b1v = *(const short8*)(B + (size_t)(1 * 16 + m) * 256 + kk * 32 + quad * 8);
        short8 b2v = *(const short8*)(B + (size_t)(2 * 16 + m) * 256 + kk * 32 + quad * 8);
        short8 b3v = *(const short8*)(B + (size_t)(3 * 16 + m) * 256 + kk * 32 + quad * 8);
        acc0 = __builtin_amdgcn_mfma_f32_16x16x32_bf16(af, b0, acc0, 0, 0, 0);
        acc1 = __builtin_amdgcn_mfma_f32_16x16x32_bf16(af, b1v, acc1, 0, 0, 0);
        acc2 = __builtin_amdgcn_mfma_f32_16x16x32_bf16(af, b2v, acc2, 0, 0, 0);
        acc3 = __builtin_amdgcn_mfma_f32_16x16x32_bf16(af, b3v, acc3, 0, 0, 0);
    }
    f32x4 accs[4] = {acc0, acc1, acc2, acc3};

    float vals[4][4];
#pragma unroll
    for (int cb = 0; cb < 4; cb++) {
        float bv = b2[cb * 16 + m];
#pragma unroll
        for (int r = 0; r < 4; r++)
            vals[cb][r] = fmaxf(0.25f * accs[cb][r] + bv, 0.f);
    }

    bool fast = (nodeBase + 15 < N);
    int g0 = 0;
    if (fast) {
        g0 = batch[nodeBase];
        int g1 = batch[nodeBase + 15];
        fast = (g0 == g1);
    }
    if (fast) {
#pragma unroll
        for (int cb = 0; cb < 4; cb++) {
            float s = vals[cb][0] + vals[cb][1] + vals[cb][2] + vals[cb][3];
            s += __shfl_xor(s, 16);
            s += __shfl_xor(s, 32);
            if (quad == 0) atomicAdd(&out[g0 * 64 + cb * 16 + m], s);
        }
    } else {
#pragma unroll
        for (int r = 0; r < 4; r++) {
            int node = nodeBase + quad * 4 + r;
            if (node < N) {
                int g = batch[node];
#pragma unroll
                for (int cb = 0; cb < 4; cb++)
                    atomicAdd(&out[g * 64 + cb * 16 + m], vals[cb][r]);
            }
        }
    }
}

extern "C" void kernel_launch(void* const* d_in, const int* in_sizes, int n_in,
                              void* d_out, int out_size, void* d_ws, size_t ws_size,
                              hipStream_t stream) {
    const float* x   = (const float*)d_in[0];
    const int*   ei  = (const int*)d_in[1];
    const int*   bat = (const int*)d_in[2];
    const float* W1  = (const float*)d_in[3];
    const float* as1 = (const float*)d_in[4];
    const float* ad1 = (const float*)d_in[5];
    const float* b1  = (const float*)d_in[6];
    const float* W2  = (const float*)d_in[7];
    const float* as2 = (const float*)d_in[8];
    const float* ad2 = (const float*)d_in[9];
    const float* b2  = (const float*)d_in[10];
    float* out = (float*)d_out;

    int N = in_sizes[0] / 3;
    int E = in_sizes[1] / 2;
    int G = out_size / 64;
    const int* srcI = ei;
    const int* dstI = ei + E;
    int NBUCK = (N + BWIDTH - 1) >> BSHIFT;

    // ---- workspace layout ----
    float* fw = (float*)d_ws;
    size_t fo = 0;
    unsigned short* houtb = (unsigned short*)fw; fo += (size_t)N * 32;
    float* esB   = fw + fo; fo += (size_t)N * 4;
    float* edB   = fw + fo; fo += (size_t)N * 4;
    float* p1s   = fw + fo; fo += 64;
    float* p1d   = fw + fo; fo += 64;
    float* qs    = fw + fo; fo += 256;
    float* qd    = fw + fo; fo += 256;
    unsigned short* W2bt = (unsigned short*)(fw + fo); fo += 64 * 256 / 2;
    int* iw = (int*)(fw + fo);
    size_t io = 0;
    unsigned* pairs = (unsigned*)iw; io += E;
    int* csr    = iw + io; io += E;
    int* off    = iw + io; io += N + 1;
    int* bbase  = iw + io; io += 1025;
    int* gcur   = iw + io; io += 1024;
    int* bcnt   = iw + io; io += 1024;

    int nGrpBlk = (N + 15) / 16;

    // ---- CSR build ----
    hipMemsetAsync(bcnt, 0, 1024 * sizeof(int), stream);
    k_bhist<<<256, 256, 0, stream>>>(dstI, bcnt, E, NBUCK);
    k_bscan<<<1, 1024, 0, stream>>>(bcnt, bbase, gcur, off, NBUCK, N, E);
    k_bdist<<<(E + DCHUNK - 1) / DCHUNK, 1024, 0, stream>>>(srcI, dstI, gcur, pairs, E, NBUCK);
    k_bcsr<<<NBUCK, 256, 0, stream>>>(pairs, bbase, off, csr, N);

    // ---- fused prep ----
    k_prep_all<<<198, 256, 0, stream>>>(W1, as1, ad1, W2, as2, ad2,
                                        p1s, p1d, qs, qd, W2bt, out, G * 64);

    // ---- layer 1 ----
    k_agg1<<<nGrpBlk, 256, 0, stream>>>(off, csr, x, p1s, p1d, W1, b1, qs, qd,
                                        houtb, esB, edB, N);

    // ---- layer 2 (aggregate + fused MFMA transform + pool) ----
    k_agg2<<<nGrpBlk, 256, 0, stream>>>(off, csr, esB, edB, houtb, W2bt, b2, bat, out, N);
}

// Round 17
// 225.762 us; speedup vs baseline: 1.0976x; 1.0187x over previous
//
#include <hip/hip_runtime.h>
#include <math.h>

#define HEADS 4
#define HID 64
#define BSHIFT 7          // 128 nodes per bucket
#define BWIDTH 128
#define CCAP 4096         // LDS csr-staging capacity (edges/bucket mean ~2047)
#define DCHUNK 8192       // edges per k_bdist block (8 per thread, 1024 threads)
#define APAD 264          // aggl row stride in ushorts (256 + 8 pad)

typedef __attribute__((ext_vector_type(8))) short short8;
typedef __attribute__((ext_vector_type(4))) float f32x4;
typedef __attribute__((ext_vector_type(2))) float f32x2;

__device__ __forceinline__ float lrelu(float x) { return x > 0.f ? x : 0.2f * x; }

__device__ __forceinline__ unsigned short bf16r(float f) {
    unsigned u = __float_as_uint(f);
    unsigned r = (u + 0x7FFFu + ((u >> 16) & 1u)) >> 16;
    return (unsigned short)r;
}
__device__ __forceinline__ unsigned pk2(float a, float b) {   // RNE pack (cold paths)
    return (unsigned)bf16r(a) | ((unsigned)bf16r(b) << 16);
}
// truncating bf16 pack via v_perm_b32: out = (trunc(b)<<16) | trunc(a) — 1 instr
__device__ __forceinline__ unsigned pkt(float a, float b) {
    return __builtin_amdgcn_perm(__float_as_uint(b), __float_as_uint(a), 0x07060302);
}
__device__ __forceinline__ f32x2 unpk(unsigned u) {
    f32x2 r;
    r.x = __uint_as_float(u << 16);
    r.y = __uint_as_float(u & 0xffff0000u);
    return r;
}

__device__ __forceinline__ float wred_sum(float v) {
#pragma unroll
    for (int o = 32; o > 0; o >>= 1) v += __shfl_xor(v, o);
    return v;
}
__device__ __forceinline__ float red16_sum(float v) {
#pragma unroll
    for (int o = 8; o > 0; o >>= 1) v += __shfl_xor(v, o);
    return v;
}

// ======================= CSR build: two-level LDS counting sort =======================
__global__ void k_bhist(const int* __restrict__ dstI, int* __restrict__ bcnt,
                        int E, int NBUCK) {
    __shared__ int h[1024];
    for (int i = threadIdx.x; i < NBUCK; i += 256) h[i] = 0;
    __syncthreads();
    int stride = gridDim.x * 256;
    for (int e = blockIdx.x * 256 + threadIdx.x; e < E; e += stride)
        atomicAdd(&h[dstI[e] >> BSHIFT], 1);
    __syncthreads();
    for (int i = threadIdx.x; i < NBUCK; i += 256)
        if (h[i]) atomicAdd(&bcnt[i], h[i]);
}

__global__ void k_bscan(const int* __restrict__ bcnt, int* __restrict__ bbase,
                        int* __restrict__ gcur, int* __restrict__ off,
                        int NBUCK, int N, int E) {
    __shared__ int lds[1024];
    int t = threadIdx.x;
    int v = (t < NBUCK) ? bcnt[t] : 0;
    lds[t] = v;
    __syncthreads();
    for (int s = 1; s < 1024; s <<= 1) {
        int u = (t >= s) ? lds[t - s] : 0;
        __syncthreads();
        lds[t] += u;
        __syncthreads();
    }
    if (t < NBUCK) {
        int b = lds[t] - v;
        bbase[t] = b;
        gcur[t] = b;
    }
    if (t == 0) { bbase[NBUCK] = E; off[N] = E; }
}

__global__ void k_bdist(const int* __restrict__ srcI, const int* __restrict__ dstI,
                        int* __restrict__ gcur, unsigned* __restrict__ pairs,
                        int E, int NBUCK) {
    __shared__ int h[1024];
    __shared__ int cur[1024];
    for (int i = threadIdx.x; i < NBUCK; i += 1024) h[i] = 0;
    __syncthreads();
    int base = blockIdx.x * DCHUNK;
    int sr[8], dr[8];
#pragma unroll
    for (int k = 0; k < 8; k++) {
        int e = base + threadIdx.x + k * 1024;
        if (e < E) {
            sr[k] = srcI[e];
            dr[k] = dstI[e];
            atomicAdd(&h[dr[k] >> BSHIFT], 1);
        } else dr[k] = -1;
    }
    __syncthreads();
    for (int i = threadIdx.x; i < NBUCK; i += 1024)
        cur[i] = h[i] ? atomicAdd(&gcur[i], h[i]) : 0;
    __syncthreads();
#pragma unroll
    for (int k = 0; k < 8; k++) {
        if (dr[k] >= 0) {
            int b = dr[k] >> BSHIFT;
            int p = atomicAdd(&cur[b], 1);
            pairs[p] = ((unsigned)sr[k] << BSHIFT) | ((unsigned)dr[k] & (BWIDTH - 1));
        }
    }
}

__global__ void k_bcsr(const unsigned* __restrict__ pairs, const int* __restrict__ bbase,
                       int* __restrict__ off, int* __restrict__ csr, int N) {
    __shared__ int cnt[BWIDTH];
    __shared__ int scan[BWIDTH];
    __shared__ int cur[BWIDTH];
    __shared__ int stage[CCAP];
    int b = blockIdx.x;
    int nodeBase = b << BSHIFT;
    int nNodes = N - nodeBase;
    if (nNodes > BWIDTH) nNodes = BWIDTH;
    int e0 = bbase[b], e1 = bbase[b + 1];
    int ecnt = e1 - e0;
    if (threadIdx.x < BWIDTH) cnt[threadIdx.x] = 0;
    __syncthreads();
    for (int i = threadIdx.x; i < ecnt; i += 256)
        atomicAdd(&cnt[pairs[e0 + i] & (BWIDTH - 1)], 1);
    __syncthreads();
    if (threadIdx.x < BWIDTH)
        scan[threadIdx.x] = (threadIdx.x < nNodes) ? cnt[threadIdx.x] : 0;
    __syncthreads();
    for (int s = 1; s < BWIDTH; s <<= 1) {
        int u = 0;
        if (threadIdx.x < BWIDTH && threadIdx.x >= s) u = scan[threadIdx.x - s];
        __syncthreads();
        if (threadIdx.x < BWIDTH) scan[threadIdx.x] += u;
        __syncthreads();
    }
    if (threadIdx.x < nNodes) {
        int ex = scan[threadIdx.x] - cnt[threadIdx.x];
        off[nodeBase + threadIdx.x] = e0 + ex;
        cur[threadIdx.x] = ex;
    }
    __syncthreads();
    for (int i = threadIdx.x; i < ecnt; i += 256) {
        unsigned pr = pairs[e0 + i];
        int l = atomicAdd(&cur[pr & (BWIDTH - 1)], 1);
        int src = (int)(pr >> BSHIFT);
        if (l < CCAP) stage[l] = src;
        else csr[e0 + l] = src;
    }
    __syncthreads();
    int lim = ecnt < CCAP ? ecnt : CCAP;
    for (int i = threadIdx.x; i < lim; i += 256) csr[e0 + i] = stage[i];
}

// ======================= fused prep: W1-proj, W2-proj, W2->bf16, out-zero =======================
__device__ __forceinline__ void prep_body(const float* __restrict__ W,
                                          const float* __restrict__ asrc,
                                          const float* __restrict__ adst,
                                          float* __restrict__ p_src,
                                          float* __restrict__ p_dst, int K, int blk) {
    int wid = blk * 4 + (threadIdx.x >> 6);
    int lane = threadIdx.x & 63;
    int total = K * 4 * 2;
    if (wid >= total) return;
    int which = wid / (K * 4);
    int hk = wid % (K * 4);
    int h = hk / K, k = hk % K;
    const float* a = which ? adst : asrc;
    float v = W[(size_t)k * 256 + h * 64 + lane] * a[h * 64 + lane];
    v = wred_sum(v);
    if (lane == 0) (which ? p_dst : p_src)[h * K + k] = v;
}

__global__ void k_prep_all(const float* __restrict__ W1, const float* __restrict__ as1,
                           const float* __restrict__ ad1, const float* __restrict__ W2,
                           const float* __restrict__ as2, const float* __restrict__ ad2,
                           float* __restrict__ p1s, float* __restrict__ p1d,
                           float* __restrict__ qs, float* __restrict__ qd,
                           unsigned short* __restrict__ W2bt, float* __restrict__ out,
                           int outTotal) {
    int b = blockIdx.x;
    if (b < 6) {
        prep_body(W1, as1, ad1, p1s, p1d, 3, b);
    } else if (b < 134) {
        prep_body(W2, as2, ad2, qs, qd, 64, b - 6);
    } else {
        int i = (b - 134) * 256 + threadIdx.x;
        int c = i >> 8, kh = i & 255;
        int h = kh >> 6, kf = kh & 63;
        W2bt[i] = bf16r(W2[kf * 256 + h * 64 + c]);
        if (i < outTotal) out[i] = 0.f;
    }
}

// ======================= layer 1: 16-lane group per node, single pass =======================
__global__ void k_agg1(const int* __restrict__ off, const int* __restrict__ csr,
                       const float* __restrict__ x, const float* __restrict__ ps,
                       const float* __restrict__ pd, const float* __restrict__ W1,
                       const float* __restrict__ b1, const float* __restrict__ qs,
                       const float* __restrict__ qd, unsigned short* __restrict__ houtb,
                       float* __restrict__ es2, float* __restrict__ ed2, int N) {
    int grp = (blockIdx.x * blockDim.x + threadIdx.x) >> 4;
    int l = threadIdx.x & 15;
    int wid = grp;
    bool active = wid < N;
    int o0 = 0, deg = 0;
    float ed0 = 0.f, ed1 = 0.f, ed2v = 0.f, ed3 = 0.f;
    if (active) {
        o0 = off[wid];
        deg = off[wid + 1] - o0;
        float y0 = x[wid * 3], y1 = x[wid * 3 + 1], y2 = x[wid * 3 + 2];
        ed0 = y0 * pd[0] + y1 * pd[1] + y2 * pd[2];
        ed1 = y0 * pd[3] + y1 * pd[4] + y2 * pd[5];
        ed2v = y0 * pd[6] + y1 * pd[7] + y2 * pd[8];
        ed3 = y0 * pd[9] + y1 * pd[10] + y2 * pd[11];
    }

    float t0 = 0.f, t1 = 0.f, t2 = 0.f, t3 = 0.f;
    float a00 = 0, a01 = 0, a02 = 0, a10 = 0, a11 = 0, a12 = 0;
    float a20 = 0, a21 = 0, a22 = 0, a30 = 0, a31 = 0, a32 = 0;
    for (int j = l; j < deg; j += 16) {
        int s = csr[o0 + j];
        float xv0 = x[s * 3], xv1 = x[s * 3 + 1], xv2 = x[s * 3 + 2];
        float e0 = __expf(lrelu(xv0 * ps[0] + xv1 * ps[1] + xv2 * ps[2] + ed0));
        float e1 = __expf(lrelu(xv0 * ps[3] + xv1 * ps[4] + xv2 * ps[5] + ed1));
        float e2 = __expf(lrelu(xv0 * ps[6] + xv1 * ps[7] + xv2 * ps[8] + ed2v));
        float e3 = __expf(lrelu(xv0 * ps[9] + xv1 * ps[10] + xv2 * ps[11] + ed3));
        t0 += e0; t1 += e1; t2 += e2; t3 += e3;
        a00 += e0 * xv0; a01 += e0 * xv1; a02 += e0 * xv2;
        a10 += e1 * xv0; a11 += e1 * xv1; a12 += e1 * xv2;
        a20 += e2 * xv0; a21 += e2 * xv1; a22 += e2 * xv2;
        a30 += e3 * xv0; a31 += e3 * xv1; a32 += e3 * xv2;
    }
    t0 = red16_sum(t0); t1 = red16_sum(t1); t2 = red16_sum(t2); t3 = red16_sum(t3);
    float i0 = t0 > 0.f ? 1.f / t0 : 0.f;
    float i1 = t1 > 0.f ? 1.f / t1 : 0.f;
    float i2 = t2 > 0.f ? 1.f / t2 : 0.f;
    float i3 = t3 > 0.f ? 1.f / t3 : 0.f;
    a00 = red16_sum(a00) * i0; a01 = red16_sum(a01) * i0; a02 = red16_sum(a02) * i0;
    a10 = red16_sum(a10) * i1; a11 = red16_sum(a11) * i1; a12 = red16_sum(a12) * i1;
    a20 = red16_sum(a20) * i2; a21 = red16_sum(a21) * i2; a22 = red16_sum(a22) * i2;
    a30 = red16_sum(a30) * i3; a31 = red16_sum(a31) * i3; a32 = red16_sum(a32) * i3;

    if (!active) return;

    const float4* W1f = (const float4*)W1;
    float4 r = make_float4(0.f, 0.f, 0.f, 0.f);
    float ah[4][3] = {{a00, a01, a02}, {a10, a11, a12}, {a20, a21, a22}, {a30, a31, a32}};
#pragma unroll
    for (int k = 0; k < 3; k++) {
#pragma unroll
        for (int h = 0; h < 4; h++) {
            float4 wv = W1f[k * 64 + h * 16 + l];
            float a = ah[h][k];
            r.x += a * wv.x; r.y += a * wv.y; r.z += a * wv.z; r.w += a * wv.w;
        }
    }
    float4 bv = ((const float4*)b1)[l];
    float4 hv;
    hv.x = fmaxf(0.25f * r.x + bv.x, 0.f);
    hv.y = fmaxf(0.25f * r.y + bv.y, 0.f);
    hv.z = fmaxf(0.25f * r.z + bv.z, 0.f);
    hv.w = fmaxf(0.25f * r.w + bv.w, 0.f);
    ((ushort4*)houtb)[(size_t)wid * 16 + l] =
        make_ushort4(bf16r(hv.x), bf16r(hv.y), bf16r(hv.z), bf16r(hv.w));

    const float4* qsf = (const float4*)qs;
    const float4* qdf = (const float4*)qd;
    float psv[4], pdv[4];
#pragma unroll
    for (int h = 0; h < 4; h++) {
        float4 q = qsf[h * 16 + l];
        psv[h] = red16_sum(hv.x * q.x + hv.y * q.y + hv.z * q.z + hv.w * q.w);
        float4 p = qdf[h * 16 + l];
        pdv[h] = red16_sum(hv.x * p.x + hv.y * p.y + hv.z * p.z + hv.w * p.w);
    }
    if (l == 0) {
        ((float4*)es2)[wid] = make_float4(psv[0], psv[1], psv[2], psv[3]);
        ((float4*)ed2)[wid] = make_float4(pdv[0], pdv[1], pdv[2], pdv[3]);
    }
}

// ======================= layer 2: softmax + gather + fused MFMA transform + pool =======================
#define NS 16
__global__ void k_agg2(const int* __restrict__ off, const int* __restrict__ csr,
                       const float* __restrict__ es, const float* __restrict__ ed,
                       const unsigned short* __restrict__ houtb,
                       const unsigned short* __restrict__ W2bt,
                       const float* __restrict__ b2, const int* __restrict__ batch,
                       float* __restrict__ out, int N) {
    __shared__ unsigned exl[NS * 64 * 2];       // 8 KB: (e0|e1, e2|e3) bf16 packed
    __shared__ int   sl[NS * 64];               // 4 KB
    __shared__ float minv[NS * 4];
    __shared__ int   meta[NS * 2];
    __shared__ unsigned short aggl[NS * APAD];  // 8.25 KB

    int l = threadIdx.x & 15;
    int slot = threadIdx.x >> 4;
    int wid = blockIdx.x * NS + slot;
    bool active = wid < N;
    int o0 = 0, deg = 0;
    float4 edv = make_float4(0.f, 0.f, 0.f, 0.f);
    if (active) {
        o0 = off[wid];
        deg = off[wid + 1] - o0;
        edv = ((const float4*)ed)[wid];
    }

    // phase A: exp (no max) -> trunc-packed bf16 LDS (first 64 edges) + fp32 sum
    float t0 = 0.f, t1 = 0.f, t2 = 0.f, t3 = 0.f;
    for (int j = l; j < deg; j += 16) {
        int s = csr[o0 + j];
        float4 ev = ((const float4*)es)[s];
        float e0 = __expf(lrelu(ev.x + edv.x));
        float e1 = __expf(lrelu(ev.y + edv.y));
        float e2 = __expf(lrelu(ev.z + edv.z));
        float e3 = __expf(lrelu(ev.w + edv.w));
        if (j < 64) {
            ((uint2*)exl)[slot * 64 + j] = make_uint2(pkt(e0, e1), pkt(e2, e3));
            sl[slot * 64 + j] = s;
        }
        t0 += e0; t1 += e1; t2 += e2; t3 += e3;
    }
    {
        int dmain = deg < 64 ? deg : 64;
        int d8 = (dmain + 7) & ~7;
        if (dmain + l < d8) {
            ((uint2*)exl)[slot * 64 + dmain + l] = make_uint2(0u, 0u);
            sl[slot * 64 + dmain + l] = 0;
        }
    }
    if (!active) {
        for (int i = l; i < 128; i += 16)
            ((unsigned*)(aggl + slot * APAD))[i] = 0u;
    }
    t0 = red16_sum(t0); t1 = red16_sum(t1); t2 = red16_sum(t2); t3 = red16_sum(t3);
    if (l == 0) {
        minv[slot * 4 + 0] = t0 > 0.f ? 1.f / t0 : 0.f;
        minv[slot * 4 + 1] = t1 > 0.f ? 1.f / t1 : 0.f;
        minv[slot * 4 + 2] = t2 > 0.f ? 1.f / t2 : 0.f;
        minv[slot * 4 + 3] = t3 > 0.f ? 1.f / t3 : 0.f;
        meta[slot * 2 + 0] = o0;
        meta[slot * 2 + 1] = deg;
    }
    __syncthreads();

    int lane = threadIdx.x & 63;
    int w = threadIdx.x >> 6;
    int half = lane >> 5;
    int c2 = lane & 31;
    for (int sidx = 0; sidx < 4; sidx++) {
        int slot2 = w * 4 + sidx;
        int nd = blockIdx.x * NS + slot2;
        if (nd >= N) continue;
        int o0b = meta[slot2 * 2 + 0], degb = meta[slot2 * 2 + 1];
        float iv0 = minv[slot2 * 4 + 0], iv1 = minv[slot2 * 4 + 1];
        float iv2 = minv[slot2 * 4 + 2], iv3 = minv[slot2 * 4 + 3];

        f32x2 q0 = {0.f, 0.f}, q1 = {0.f, 0.f}, q2 = {0.f, 0.f}, q3 = {0.f, 0.f};
        const uint2* EX = ((const uint2*)exl) + slot2 * 64;
        const int* S = sl + slot2 * 64;
        int dmain = degb < 64 ? degb : 64;
        int d8 = (dmain + 7) & ~7;
        for (int j = 0; j < d8; j += 8) {
            uint2 ua = EX[j + half];
            uint2 ub = EX[j + 2 + half];
            uint2 uc = EX[j + 4 + half];
            uint2 ud = EX[j + 6 + half];
            int s0 = S[j + half], s1 = S[j + 2 + half];
            int s2 = S[j + 4 + half], s3 = S[j + 6 + half];
            unsigned u0 = *(const unsigned*)(houtb + (size_t)s0 * 64 + 2 * c2);
            unsigned u1 = *(const unsigned*)(houtb + (size_t)s1 * 64 + 2 * c2);
            unsigned u2 = *(const unsigned*)(houtb + (size_t)s2 * 64 + 2 * c2);
            unsigned u3 = *(const unsigned*)(houtb + (size_t)s3 * 64 + 2 * c2);
            f32x2 v0 = unpk(u0), v1 = unpk(u1), v2 = unpk(u2), v3 = unpk(u3);
            f32x2 a01v = unpk(ua.x), a23v = unpk(ua.y);
            f32x2 b01v = unpk(ub.x), b23v = unpk(ub.y);
            f32x2 c01v = unpk(uc.x), c23v = unpk(uc.y);
            f32x2 d01v = unpk(ud.x), d23v = unpk(ud.y);
            q0 += a01v.x * v0; q0 += b01v.x * v1; q0 += c01v.x * v2; q0 += d01v.x * v3;
            q1 += a01v.y * v0; q1 += b01v.y * v1; q1 += c01v.y * v2; q1 += d01v.y * v3;
            q2 += a23v.x * v0; q2 += b23v.x * v1; q2 += c23v.x * v2; q2 += d23v.x * v3;
            q3 += a23v.y * v0; q3 += b23v.y * v1; q3 += c23v.y * v2; q3 += d23v.y * v3;
        }
        if (degb > 64) {
            float4 edv2 = ((const float4*)ed)[nd];
            for (int j = 64 + half; j < degb; j += 2) {
                int s = csr[o0b + j];
                float4 ev = ((const float4*)es)[s];
                float e0 = __expf(lrelu(ev.x + edv2.x));
                float e1 = __expf(lrelu(ev.y + edv2.y));
                float e2 = __expf(lrelu(ev.z + edv2.z));
                float e3 = __expf(lrelu(ev.w + edv2.w));
                unsigned u = *(const unsigned*)(houtb + (size_t)s * 64 + 2 * c2);
                f32x2 v = unpk(u);
                q0 += e0 * v; q1 += e1 * v; q2 += e2 * v; q3 += e3 * v;
            }
        }
        q0.x += __shfl_xor(q0.x, 32); q0.y += __shfl_xor(q0.y, 32);
        q1.x += __shfl_xor(q1.x, 32); q1.y += __shfl_xor(q1.y, 32);
        q2.x += __shfl_xor(q2.x, 32); q2.y += __shfl_xor(q2.y, 32);
        q3.x += __shfl_xor(q3.x, 32); q3.y += __shfl_xor(q3.y, 32);

        if (half == 0) {
            unsigned short* arow = aggl + slot2 * APAD;
            *(unsigned*)(arow + 2 * c2)        = pk2(q0.x * iv0, q0.y * iv0);
            *(unsigned*)(arow + 64 + 2 * c2)   = pk2(q1.x * iv1, q1.y * iv1);
            *(unsigned*)(arow + 128 + 2 * c2)  = pk2(q2.x * iv2, q2.y * iv2);
            *(unsigned*)(arow + 192 + 2 * c2)  = pk2(q3.x * iv3, q3.y * iv3);
        }
    }
    __syncthreads();

    // ---- epilogue (wave 0 only): MFMA transform + bias/relu + pooled atomics ----
    if (w != 0) return;
    int nodeBase = blockIdx.x * NS;
    int m = lane & 15;
    int quad = lane >> 4;
    const short* A = (const short*)aggl + m * APAD + quad * 8;
    const short* B = (const short*)W2bt;

    f32x4 acc0 = {0.f, 0.f, 0.f, 0.f}, acc1 = {0.f, 0.f, 0.f, 0.f};
    f32x4 acc2 = {0.f, 0.f, 0.f, 0.f}, acc3 = {0.f, 0.f, 0.f, 0.f};
#pragma unroll
    for (int kk = 0; kk < 8; kk++) {
        short8 af = *(const short8*)(A + kk * 32);
        short8 b0 = *(const short8*)(B + (size_t)(0 * 16 + m) * 256 + kk * 32 + quad * 8);
        short8 b1v = *(const short8*)(B + (size_t)(1 * 16 + m) * 256 + kk * 32 + quad * 8);
        short8 b2v = *(const short8*)(B + (size_t)(2 * 16 + m) * 256 + kk * 32 + quad * 8);
        short8 b3v = *(const short8*)(B + (size_t)(3 * 16 + m) * 256 + kk * 32 + quad * 8);
        acc0 = __builtin_amdgcn_mfma_f32_16x16x32_bf16(af, b0, acc0, 0, 0, 0);
        acc1 = __builtin_amdgcn_mfma_f32_16x16x32_bf16(af, b1v, acc1, 0, 0, 0);
        acc2 = __builtin_amdgcn_mfma_f32_16x16x32_bf16(af, b2v, acc2, 0, 0, 0);
        acc3 = __builtin_amdgcn_mfma_f32_16x16x32_bf16(af, b3v, acc3, 0, 0, 0);
    }
    f32x4 accs[4] = {acc0, acc1, acc2, acc3};

    float vals[4][4];
#pragma unroll
    for (int cb = 0; cb < 4; cb++) {
        float bv = b2[cb * 16 + m];
#pragma unroll
        for (int r = 0; r < 4; r++)
            vals[cb][r] = fmaxf(0.25f * accs[cb][r] + bv, 0.f);
    }

    bool fast = (nodeBase + 15 < N);
    int g0 = 0;
    if (fast) {
        g0 = batch[nodeBase];
        int g1 = batch[nodeBase + 15];
        fast = (g0 == g1);
    }
    if (fast) {
#pragma unroll
        for (int cb = 0; cb < 4; cb++) {
            float s = vals[cb][0] + vals[cb][1] + vals[cb][2] + vals[cb][3];
            s += __shfl_xor(s, 16);
            s += __shfl_xor(s, 32);
            if (quad == 0) atomicAdd(&out[g0 * 64 + cb * 16 + m], s);
        }
    } else {
#pragma unroll
        for (int r = 0; r < 4; r++) {
            int node = nodeBase + quad * 4 + r;
            if (node < N) {
                int g = batch[node];
#pragma unroll
                for (int cb = 0; cb < 4; cb++)
                    atomicAdd(&out[g * 64 + cb * 16 + m], vals[cb][r]);
            }
        }
    }
}

extern "C" void kernel_launch(void* const* d_in, const int* in_sizes, int n_in,
                              void* d_out, int out_size, void* d_ws, size_t ws_size,
                              hipStream_t stream) {
    const float* x   = (const float*)d_in[0];
    const int*   ei  = (const int*)d_in[1];
    const int*   bat = (const int*)d_in[2];
    const float* W1  = (const float*)d_in[3];
    const float* as1 = (const float*)d_in[4];
    const float* ad1 = (const float*)d_in[5];
    const float* b1  = (const float*)d_in[6];
    const float* W2  = (const float*)d_in[7];
    const float* as2 = (const float*)d_in[8];
    const float* ad2 = (const float*)d_in[9];
    const float* b2  = (const float*)d_in[10];
    float* out = (float*)d_out;

    int N = in_sizes[0] / 3;
    int E = in_sizes[1] / 2;
    int G = out_size / 64;
    const int* srcI = ei;
    const int* dstI = ei + E;
    int NBUCK = (N + BWIDTH - 1) >> BSHIFT;

    // ---- workspace layout ----
    float* fw = (float*)d_ws;
    size_t fo = 0;
    unsigned short* houtb = (unsigned short*)fw; fo += (size_t)N * 32;
    float* esB   = fw + fo; fo += (size_t)N * 4;
    float* edB   = fw + fo; fo += (size_t)N * 4;
    float* p1s   = fw + fo; fo += 64;
    float* p1d   = fw + fo; fo += 64;
    float* qs    = fw + fo; fo += 256;
    float* qd    = fw + fo; fo += 256;
    unsigned short* W2bt = (unsigned short*)(fw + fo); fo += 64 * 256 / 2;
    int* iw = (int*)(fw + fo);
    size_t io = 0;
    unsigned* pairs = (unsigned*)iw; io += E;
    int* csr    = iw + io; io += E;
    int* off    = iw + io; io += N + 1;
    int* bbase  = iw + io; io += 1025;
    int* gcur   = iw + io; io += 1024;
    int* bcnt   = iw + io; io += 1024;

    int nGrpBlk = (N + 15) / 16;

    // ---- CSR build ----
    hipMemsetAsync(bcnt, 0, 1024 * sizeof(int), stream);
    k_bhist<<<256, 256, 0, stream>>>(dstI, bcnt, E, NBUCK);
    k_bscan<<<1, 1024, 0, stream>>>(bcnt, bbase, gcur, off, NBUCK, N, E);
    k_bdist<<<(E + DCHUNK - 1) / DCHUNK, 1024, 0, stream>>>(srcI, dstI, gcur, pairs, E, NBUCK);
    k_bcsr<<<NBUCK, 256, 0, stream>>>(pairs, bbase, off, csr, N);

    // ---- fused prep ----
    k_prep_all<<<198, 256, 0, stream>>>(W1, as1, ad1, W2, as2, ad2,
                                        p1s, p1d, qs, qd, W2bt, out, G * 64);

    // ---- layer 1 ----
    k_agg1<<<nGrpBlk, 256, 0, stream>>>(off, csr, x, p1s, p1d, W1, b1, qs, qd,
                                        houtb, esB, edB, N);

    // ---- layer 2 (aggregate + fused MFMA transform + pool) ----
    k_agg2<<<nGrpBlk, 256, 0, stream>>>(off, csr, esB, edB, houtb, W2bt, b2, bat, out, N);
}